// Round 13
// baseline (372.876 us; speedup 1.0000x reference)
//
#include <hip/hip_runtime.h>
#include <hip/hip_fp16.h>
#include <math.h>

typedef unsigned long long u64;
typedef __attribute__((ext_vector_type(2))) _Float16 half2v;
typedef __attribute__((ext_vector_type(4))) _Float16 half4v;

// ============================================================================
// CSR build = counting sort with coalesced writes. Edge record u32:
// [31:17] = fp16-bits-of-attr >> 1, [16:0] = src.
// k_part fused with layer-1 node transform; dst values register-cached
// between its count and scatter passes.
// k_build uses 1024-thread blocks (16 waves) for latency hiding.
// Edge phase: wave handles 4 consecutive dsts (prologue amortized, next-dst
// xr prefetch), 16-lane x 4-edge packed-fp16, unroll x2 inside each dst.
// ============================================================================

#define MAXSPAN 12032   // max csr slots per bucket (mean ~8450)

// ---------- CSR build ----------

__global__ void k_hist(const int* __restrict__ ei, int* __restrict__ qcount,
                       int E, int epb) {
    __shared__ int h[256];
    int t = threadIdx.x;
    h[t] = 0;
    __syncthreads();
    int base = blockIdx.x * epb;
    int end = base + epb; if (end > E) end = E;
    for (int e = base + t; e < end; e += 256) {
        int d = ei[E + e];
        atomicAdd(&h[d >> 8], 1);
    }
    __syncthreads();
    int c = h[t];
    if (c) atomicAdd(&qcount[t], c);
}

__global__ void k_bscan(const int* __restrict__ qcount, int* __restrict__ qbase,
                        int* __restrict__ qtail, int* __restrict__ csrbase,
                        int* __restrict__ row_start, int N, int E, int NB) {
    __shared__ int s[256], s2[256];
    int t = threadIdx.x;
    int lo = t * 256;
    int ndst = (lo < N) ? ((N - lo < 256) ? (N - lo) : 256) : 0;
    int qc = (t < NB) ? qcount[t] : 0;
    s[t] = qc; s2[t] = qc + ndst;
    __syncthreads();
    for (int off = 1; off < 256; off <<= 1) {
        int a = (t >= off) ? s[t - off] : 0;
        int b = (t >= off) ? s2[t - off] : 0;
        __syncthreads();
        s[t] += a; s2[t] += b;
        __syncthreads();
    }
    if (t < NB) {
        qbase[t] = s[t] - qc;
        qtail[t] = s[t] - qc;
        csrbase[t] = s2[t] - (qc + ndst);
    }
    if (t == 255) {
        qbase[NB] = s[255];
        csrbase[NB] = s2[255];
        row_start[N] = s2[255];
    }
}

#define PEPB 4096   // edges per partition block (16 per thread -> reg cache)

// FUSED: blocks [0,nbXF) = layer-1 node transform; blocks [nbXF,..) = k_part
__global__ void k_xf1_part(
        const float* __restrict__ h, int ld_log2,
        const float* __restrict__ Wl, const float* __restrict__ bl,
        const float* __restrict__ Wr, const float* __restrict__ br,
        __half* __restrict__ xl, __half* __restrict__ xr, int N, int nbXF,
        const int* __restrict__ ei, const float* __restrict__ ea,
        int* __restrict__ qtail, u64* __restrict__ queue, int E) {
    __shared__ float rows[16][128];
    __shared__ int lh[256], lbase[256], lcur[256];
    int t = threadIdx.x;
    if (blockIdx.x < nbXF) {
        // ---- node transform ----
        int in_dim = 1 << ld_log2;
        int node0 = blockIdx.x * 16;
        for (int idx = t; idx < (16 << ld_log2); idx += 256) {
            int nn = idx >> ld_log2, kk = idx & (in_dim - 1);
            int node = node0 + nn;
            rows[nn][kk] = (node < N) ? h[(((size_t)node) << ld_log2) + kk] : 0.f;
        }
        __syncthreads();
        int lane = t & 63, w = t >> 6;
        int nb = w * 4;
        float bl_ = bl[lane], br_ = br[lane];
        float al0 = bl_, al1 = bl_, al2 = bl_, al3 = bl_;
        float ar0 = br_, ar1 = br_, ar2 = br_, ar3 = br_;
#pragma unroll 4
        for (int k = 0; k < in_dim; ++k) {
            float wl = Wl[k * 64 + lane], wr = Wr[k * 64 + lane];
            float x0 = rows[nb][k], x1 = rows[nb + 1][k], x2 = rows[nb + 2][k], x3 = rows[nb + 3][k];
            al0 += x0 * wl; ar0 += x0 * wr;
            al1 += x1 * wl; ar1 += x1 * wr;
            al2 += x2 * wl; ar2 += x2 * wr;
            al3 += x3 * wl; ar3 += x3 * wr;
        }
        int n0 = node0 + nb;
        if (n0 + 0 < N) { xl[((size_t)(n0 + 0) << 6) + lane] = __float2half(al0); xr[((size_t)(n0 + 0) << 6) + lane] = __float2half(ar0); }
        if (n0 + 1 < N) { xl[((size_t)(n0 + 1) << 6) + lane] = __float2half(al1); xr[((size_t)(n0 + 1) << 6) + lane] = __float2half(ar1); }
        if (n0 + 2 < N) { xl[((size_t)(n0 + 2) << 6) + lane] = __float2half(al2); xr[((size_t)(n0 + 2) << 6) + lane] = __float2half(ar2); }
        if (n0 + 3 < N) { xl[((size_t)(n0 + 3) << 6) + lane] = __float2half(al3); xr[((size_t)(n0 + 3) << 6) + lane] = __float2half(ar3); }
    } else {
        // ---- edge partition into bucket queues (dst reg-cached) ----
        int pb = blockIdx.x - nbXF;
        lh[t] = 0; lcur[t] = 0;
        __syncthreads();
        int base = pb * PEPB;
        int end = base + PEPB; if (end > E) end = E;
        int dreg[PEPB / 256];
#pragma unroll
        for (int k = 0; k < PEPB / 256; ++k) {
            int e = base + t + k * 256;
            if (e < end) {
                dreg[k] = ei[E + e];
                atomicAdd(&lh[dreg[k] >> 8], 1);
            }
        }
        __syncthreads();
        if (lh[t]) lbase[t] = atomicAdd(&qtail[t], lh[t]);
        __syncthreads();
#pragma unroll
        for (int k = 0; k < PEPB / 256; ++k) {
            int e = base + t + k * 256;
            if (e < end) {
                int d = dreg[k];
                int src = ei[e];
                float a = ea[e];
                int b = d >> 8;
                int idx = atomicAdd(&lcur[b], 1);
                unsigned aq = (unsigned)(a * 16777216.0f);    // fixed-24, attr in [0,1)
                queue[lbase[b] + idx] = (((u64)aq) << 25) | (((u64)(d & 255)) << 17) | (unsigned)src;
            }
        }
    }
}

__device__ __forceinline__ unsigned attr_q15(float a) {
    unsigned short hb = __builtin_bit_cast(unsigned short, (_Float16)a);
    return (unsigned)(hb >> 1);       // attr in [0,1) -> fp16 top bit 0
}

// 1024 threads (16 waves) per bucket for latency hiding
__global__ void __launch_bounds__(1024)
k_build(const u64* __restrict__ queue, const int* __restrict__ qbase,
        const int* __restrict__ csrbase,
        int* __restrict__ row_start, unsigned* __restrict__ csr, int N) {
    __shared__ u64 stat[256];
    __shared__ int fill[256], sc[256];
    __shared__ unsigned lcsr[MAXSPAN];
    int t = threadIdx.x, b = blockIdx.x;
    if (t < 256) stat[t] = 0;
    __syncthreads();
    int q0 = qbase[b], q1 = qbase[b + 1];
    for (int i = q0 + t; i < q1; i += 1024) {
        u64 r = queue[i];
        int dl = (int)((r >> 17) & 255);
        atomicAdd(&stat[dl], (1ULL << 32) | (unsigned)(r >> 25));
    }
    __syncthreads();
    int dg = b * 256 + t;
    u64 p = (t < 256) ? stat[t] : 0;
    int deg = (int)(p >> 32);
    int v = (t < 256 && dg < N) ? deg + 1 : 0;
    if (t < 256) sc[t] = v;
    __syncthreads();
    for (int off = 1; off < 256; off <<= 1) {
        int a = (t >= off && t < 256) ? sc[t - off] : 0;
        __syncthreads();
        if (t < 256) sc[t] += a;
        __syncthreads();
    }
    if (t < 256 && dg < N) {
        int basel = sc[t] - v;   // exclusive
        row_start[dg] = csrbase[b] + basel;
        fill[t] = basel;
        float mean = ((float)(unsigned)p * (1.0f / 16777216.0f)) / fmaxf((float)deg, 1.0f);
        if (basel + deg < MAXSPAN) lcsr[basel + deg] = (attr_q15(mean) << 17) | (unsigned)dg;
    }
    __syncthreads();
    for (int i = q0 + t; i < q1; i += 1024) {
        u64 r = queue[i];
        int dl = (int)((r >> 17) & 255);
        int pos = atomicAdd(&fill[dl], 1);
        float av = (float)(unsigned)(r >> 25) * (1.0f / 16777216.0f);
        if (pos < MAXSPAN) lcsr[pos] = (attr_q15(av) << 17) | (unsigned)(r & 0x1FFFFu);
    }
    __syncthreads();
    int c0 = csrbase[b], span = csrbase[b + 1] - c0;
    if (span > MAXSPAN) span = MAXSPAN;
    for (int j = t; j < span; j += 1024) csr[c0 + j] = lcsr[j];
}

// ---------- node transform (standalone, layer 2) ----------
__global__ void k_node_xf(const float* __restrict__ h, int ld_log2,
                          const float* __restrict__ Wl, const float* __restrict__ bl,
                          const float* __restrict__ Wr, const float* __restrict__ br,
                          __half* __restrict__ xl, __half* __restrict__ xr, int N) {
    __shared__ float rows[16][128];
    int tid = threadIdx.x;
    int in_dim = 1 << ld_log2;
    int node0 = blockIdx.x * 16;
    for (int idx = tid; idx < (16 << ld_log2); idx += 256) {
        int nn = idx >> ld_log2, kk = idx & (in_dim - 1);
        int node = node0 + nn;
        rows[nn][kk] = (node < N) ? h[(((size_t)node) << ld_log2) + kk] : 0.f;
    }
    __syncthreads();
    int lane = tid & 63, w = tid >> 6;
    int nb = w * 4;
    float bl_ = bl[lane], br_ = br[lane];
    float al0 = bl_, al1 = bl_, al2 = bl_, al3 = bl_;
    float ar0 = br_, ar1 = br_, ar2 = br_, ar3 = br_;
#pragma unroll 4
    for (int k = 0; k < in_dim; ++k) {
        float wl = Wl[k * 64 + lane], wr = Wr[k * 64 + lane];
        float x0 = rows[nb][k], x1 = rows[nb + 1][k], x2 = rows[nb + 2][k], x3 = rows[nb + 3][k];
        al0 += x0 * wl; ar0 += x0 * wr;
        al1 += x1 * wl; ar1 += x1 * wr;
        al2 += x2 * wl; ar2 += x2 * wr;
        al3 += x3 * wl; ar3 += x3 * wr;
    }
    int n0 = node0 + nb;
    if (n0 + 0 < N) { xl[((size_t)(n0 + 0) << 6) + lane] = __float2half(al0); xr[((size_t)(n0 + 0) << 6) + lane] = __float2half(ar0); }
    if (n0 + 1 < N) { xl[((size_t)(n0 + 1) << 6) + lane] = __float2half(al1); xr[((size_t)(n0 + 1) << 6) + lane] = __float2half(ar1); }
    if (n0 + 2 < N) { xl[((size_t)(n0 + 2) << 6) + lane] = __float2half(al2); xr[((size_t)(n0 + 2) << 6) + lane] = __float2half(ar2); }
    if (n0 + 3 < N) { xl[((size_t)(n0 + 3) << 6) + lane] = __float2half(al3); xr[((size_t)(n0 + 3) << 6) + lane] = __float2half(ar3); }
}

#define DPW 4   // dsts per wave in k_attn

// ---------- edge phase: wave handles DPW consecutive dsts ----------
__global__ void k_attn(const __half* __restrict__ xl, const __half* __restrict__ xr,
                       const unsigned* __restrict__ csr, const int* __restrict__ row_start,
                       const float* __restrict__ We, const float* __restrict__ att,
                       const float* __restrict__ bias,
                       float* __restrict__ hout, int N) {
    int lane = threadIdx.x & 63;
    int wave = (int)(((size_t)blockIdx.x * blockDim.x + threadIdx.x) >> 6);
    int d0 = wave * DPW;
    if (d0 >= N) return;
    int dEnd = d0 + DPW; if (dEnd > N) dEnd = N;
    int eq = lane >> 4;           // which of 4 concurrent edges
    int fl = lane & 15;           // which 4-dim chunk of the 64 dims
    float4 Wef  = *(const float4*)(We + fl * 4);
    float4 attf = *(const float4*)(att + fl * 4);
    float4 b4   = *(const float4*)(bias + fl * 4);
    half2v We01 = {(_Float16)Wef.x, (_Float16)Wef.y};
    half2v We23 = {(_Float16)Wef.z, (_Float16)Wef.w};
    half2v at01 = {(_Float16)attf.x, (_Float16)attf.y};
    half2v at23 = {(_Float16)attf.z, (_Float16)attf.w};
    const half2v k02 = {(_Float16)0.2f, (_Float16)0.2f};
    // prefetch first dst's xr + row bound
    half4v xrh_n = *(const half4v*)(xr + ((size_t)d0 << 6) + fl * 4);
    int e0 = __builtin_amdgcn_readfirstlane(row_start[d0]);
    for (int d = d0; d < dEnd; ++d) {
        int e1 = __builtin_amdgcn_readfirstlane(row_start[d + 1]);
        half4v xrh = xrh_n;
        if (d + 1 < dEnd)   // prefetch next dst's xr row (overlaps edge loop)
            xrh_n = *(const half4v*)(xr + ((size_t)(d + 1) << 6) + fl * 4);
        half2v xr01 = {xrh.x, xrh.y}, xr23 = {xrh.z, xrh.w};
        float l = 0.f;
        float4 O = {0.f, 0.f, 0.f, 0.f};
        int e = e0;
        for (; e + 8 <= e1; e += 8) {       // 8 edges in flight
            unsigned rA = csr[e + eq];
            unsigned rB = csr[e + 4 + eq];
            half4v xA = *(const half4v*)(xl + (((size_t)(rA & 0x1FFFFu)) << 6) + fl * 4);
            half4v xB = *(const half4v*)(xl + (((size_t)(rB & 0x1FFFFu)) << 6) + fl * 4);
            _Float16 ahA = __builtin_bit_cast(_Float16, (unsigned short)((rA >> 16) & 0xFFFEu));
            _Float16 ahB = __builtin_bit_cast(_Float16, (unsigned short)((rB >> 16) & 0xFFFEu));
            half2v aaA = {ahA, ahA}, aaB = {ahB, ahB};
            half2v xA01 = {xA.x, xA.y}, xA23 = {xA.z, xA.w};
            half2v xB01 = {xB.x, xB.y}, xB23 = {xB.z, xB.w};
            half2v vA01 = aaA * We01 + (xA01 + xr01);
            half2v vA23 = aaA * We23 + (xA23 + xr23);
            half2v vB01 = aaB * We01 + (xB01 + xr01);
            half2v vB23 = aaB * We23 + (xB23 + xr23);
            half2v sA01 = __builtin_elementwise_max(vA01, vA01 * k02);
            half2v sA23 = __builtin_elementwise_max(vA23, vA23 * k02);
            half2v sB01 = __builtin_elementwise_max(vB01, vB01 * k02);
            half2v sB23 = __builtin_elementwise_max(vB23, vB23 * k02);
#if __has_builtin(__builtin_amdgcn_fdot2)
            float cA = __builtin_amdgcn_fdot2(sA01, at01, 0.f, false);
            cA = __builtin_amdgcn_fdot2(sA23, at23, cA, false);
            float cB = __builtin_amdgcn_fdot2(sB01, at01, 0.f, false);
            cB = __builtin_amdgcn_fdot2(sB23, at23, cB, false);
#else
            float cA = (float)sA01.x * (float)at01.x + (float)sA01.y * (float)at01.y
                     + (float)sA23.x * (float)at23.x + (float)sA23.y * (float)at23.y;
            float cB = (float)sB01.x * (float)at01.x + (float)sB01.y * (float)at01.y
                     + (float)sB23.x * (float)at23.x + (float)sB23.y * (float)at23.y;
#endif
#pragma unroll
            for (int mm = 1; mm <= 8; mm <<= 1) {
                cA += __shfl_xor(cA, mm, 64);
                cB += __shfl_xor(cB, mm, 64);
            }
            float qA = __expf(cA), qB = __expf(cB);
            l += qA + qB;
            O.x = fmaf(qA, (float)xA.x, O.x); O.x = fmaf(qB, (float)xB.x, O.x);
            O.y = fmaf(qA, (float)xA.y, O.y); O.y = fmaf(qB, (float)xB.y, O.y);
            O.z = fmaf(qA, (float)xA.z, O.z); O.z = fmaf(qB, (float)xB.z, O.z);
            O.w = fmaf(qA, (float)xA.w, O.w); O.w = fmaf(qB, (float)xB.w, O.w);
        }
        for (; e < e1; e += 4) {            // tail with clamp
            int ee = e + eq;
            bool valid = ee < e1;
            unsigned r = csr[valid ? ee : (e1 - 1)];
            _Float16 ah = __builtin_bit_cast(_Float16, (unsigned short)((r >> 16) & 0xFFFEu));
            half2v aa = {ah, ah};
            half4v xh = *(const half4v*)(xl + (((size_t)(r & 0x1FFFFu)) << 6) + fl * 4);
            half2v x01 = {xh.x, xh.y}, x23 = {xh.z, xh.w};
            half2v v01 = aa * We01 + (x01 + xr01);
            half2v v23 = aa * We23 + (x23 + xr23);
            half2v s01 = __builtin_elementwise_max(v01, v01 * k02);
            half2v s23 = __builtin_elementwise_max(v23, v23 * k02);
#if __has_builtin(__builtin_amdgcn_fdot2)
            float c = __builtin_amdgcn_fdot2(s01, at01, 0.f, false);
            c = __builtin_amdgcn_fdot2(s23, at23, c, false);
#else
            float c = (float)s01.x * (float)at01.x + (float)s01.y * (float)at01.y
                    + (float)s23.x * (float)at23.x + (float)s23.y * (float)at23.y;
#endif
#pragma unroll
            for (int mm = 1; mm <= 8; mm <<= 1) c += __shfl_xor(c, mm, 64);
            float q = valid ? __expf(c) : 0.f;
            l += q;
            O.x = fmaf(q, (float)xh.x, O.x);
            O.y = fmaf(q, (float)xh.y, O.y);
            O.z = fmaf(q, (float)xh.z, O.z);
            O.w = fmaf(q, (float)xh.w, O.w);
        }
#pragma unroll
        for (int mm = 16; mm <= 32; mm <<= 1) {
            l   += __shfl_xor(l, mm, 64);
            O.x += __shfl_xor(O.x, mm, 64);
            O.y += __shfl_xor(O.y, mm, 64);
            O.z += __shfl_xor(O.z, mm, 64);
            O.w += __shfl_xor(O.w, mm, 64);
        }
        if (eq == 0) {
            float inv = 1.0f / (l + 1e-16f);
            float4 res;
            res.x = fmaf(O.x, inv, b4.x);
            res.y = fmaf(O.y, inv, b4.y);
            res.z = fmaf(O.z, inv, b4.z);
            res.w = fmaf(O.w, inv, b4.w);
            res.x = res.x > 0.f ? res.x : expm1f(res.x);
            res.y = res.y > 0.f ? res.y : expm1f(res.y);
            res.z = res.z > 0.f ? res.z : expm1f(res.z);
            res.w = res.w > 0.f ? res.w : expm1f(res.w);
            *(float4*)(hout + ((size_t)d << 6) + fl * 4) = res;
        }
        e0 = e1;
    }
}

// ---------- pool: batch sorted -> run-length accumulate ----------
__global__ void k_pool2(const float* __restrict__ h, const int* __restrict__ batch,
                        float* __restrict__ pooled, float* __restrict__ gcnt,
                        int N, int npw) {
    int lane = threadIdx.x & 63;
    int wave = (int)(((size_t)blockIdx.x * blockDim.x + threadIdx.x) >> 6);
    int begin = wave * npw;
    if (begin >= N) return;
    int end = begin + npw; if (end > N) end = N;
    int g = batch[begin];
    float acc = 0.f, cnt = 0.f;
    for (int n = begin; n < end; ++n) {
        int gn = batch[n];
        if (gn != g) {
            atomicAdd(&pooled[((size_t)g << 6) + lane], acc);
            if (lane == 0) atomicAdd(&gcnt[g], cnt);
            g = gn; acc = 0.f; cnt = 0.f;
        }
        acc += h[((size_t)n << 6) + lane];
        cnt += 1.f;
    }
    atomicAdd(&pooled[((size_t)g << 6) + lane], acc);
    if (lane == 0) atomicAdd(&gcnt[g], cnt);
}

// ---------- MLP head ----------
__global__ void k_head(const float* __restrict__ pooled, const float* __restrict__ gcnt,
                       const float* __restrict__ W1, const float* __restrict__ b1,
                       const float* __restrict__ gam, const float* __restrict__ bet,
                       const float* __restrict__ mu, const float* __restrict__ var,
                       const float* __restrict__ W3, const float* __restrict__ b3,
                       float* __restrict__ out, int G) {
    int g = blockIdx.x * blockDim.x + threadIdx.x;
    if (g >= G) return;
    float inv = 1.0f / fmaxf(gcnt[g], 1.0f);
    float pr[64];
    for (int k = 0; k < 64; ++k) pr[k] = pooled[((size_t)g << 6) + k] * inv;
    float o = b3[0];
    for (int j = 0; j < 32; ++j) {
        float z = b1[j];
        for (int k = 0; k < 64; ++k) z += pr[k] * W1[k * 32 + j];
        z = fmaxf(z, 0.f);
        z = (z - mu[j]) / sqrtf(var[j] + 1e-5f) * gam[j] + bet[j];
        o += z * W3[j];
    }
    out[g] = o;
}

// ---------- launch ----------
extern "C" void kernel_launch(void* const* d_in, const int* in_sizes, int n_in,
                              void* d_out, int out_size, void* d_ws, size_t ws_size,
                              hipStream_t stream) {
    const float* x    = (const float*)d_in[0];
    const int*   ei   = (const int*)d_in[1];
    const float* ea   = (const float*)d_in[2];
    const int*   batch= (const int*)d_in[3];
    const float* Wl1  = (const float*)d_in[4];
    const float* bl1  = (const float*)d_in[5];
    const float* Wr1  = (const float*)d_in[6];
    const float* br1  = (const float*)d_in[7];
    const float* We1  = (const float*)d_in[8];
    const float* att1 = (const float*)d_in[9];
    const float* bi1  = (const float*)d_in[10];
    const float* Wl2  = (const float*)d_in[11];
    const float* bl2  = (const float*)d_in[12];
    const float* Wr2  = (const float*)d_in[13];
    const float* br2  = (const float*)d_in[14];
    const float* We2  = (const float*)d_in[15];
    const float* att2 = (const float*)d_in[16];
    const float* bi2  = (const float*)d_in[17];
    const float* Wf1  = (const float*)d_in[18];
    const float* bf1  = (const float*)d_in[19];
    const float* gam  = (const float*)d_in[20];
    const float* bet  = (const float*)d_in[21];
    const float* mu   = (const float*)d_in[22];
    const float* var  = (const float*)d_in[23];
    const float* Wf3  = (const float*)d_in[24];
    const float* bf3  = (const float*)d_in[25];

    const int N    = in_sizes[3];          // 50000
    const int E    = in_sizes[2];          // 1600000
    const int INd  = in_sizes[0] / N;      // 128
    const int ld1  = (INd == 128) ? 7 : 6;
    const int Etot = E + N;
    const int G    = out_size;             // 64
    const int NB   = (N + 255) / 256;      // buckets (<=256)

    // workspace carve-up (256B aligned)
    char* w = (char*)d_ws;
    auto carve = [&](size_t bytes) { char* p = w; w += (bytes + 255) & ~(size_t)255; return p; };
    __half*   xl       = (__half*)  carve((size_t)N * 64 * 2);
    __half*   xr       = (__half*)  carve((size_t)N * 64 * 2);
    float*    hbuf     = (float*)   carve((size_t)N * 64 * 4);
    unsigned* csr      = (unsigned*)carve((size_t)(Etot + 8) * 4);
    u64*      queue    = (u64*)     carve((size_t)E * 8);
    int*      row_start= (int*)     carve((size_t)(N + 1) * 4);
    int*      qcount   = (int*)     carve((size_t)256 * 4);
    int*      qbase    = (int*)     carve((size_t)257 * 4);
    int*      qtail    = (int*)     carve((size_t)256 * 4);
    int*      csrbase  = (int*)     carve((size_t)257 * 4);
    float*    pooled   = (float*)   carve((size_t)G * 64 * 4);
    float*    gcnt     = (float*)   carve((size_t)G * 4);

    const int TB = 256;
    const int nbXF = (N + 15) / 16;              // node-transform blocks
    const int attnWaves = (N + DPW - 1) / DPW;
    const int attnBlocks = (attnWaves + 3) / 4;  // 4 waves per 256-thread block

    // ---- CSR build start ----
    hipMemsetAsync(qcount, 0, 256 * 4, stream);
    const int hepb = 8192;
    k_hist<<<(E + hepb - 1) / hepb, TB, 0, stream>>>(ei, qcount, E, hepb);
    k_bscan<<<1, 256, 0, stream>>>(qcount, qbase, qtail, csrbase, row_start, N, E, NB);
    // ---- fused: layer-1 node transform || edge partition ----
    const int nbPart = (E + PEPB - 1) / PEPB;
    k_xf1_part<<<nbXF + nbPart, TB, 0, stream>>>(x, ld1, Wl1, bl1, Wr1, br1, xl, xr, N, nbXF,
                                                 ei, ea, qtail, queue, E);
    k_build<<<NB, 1024, 0, stream>>>(queue, qbase, csrbase, row_start, csr, N);

    // ---- layer 1 edge phase ----
    k_attn<<<attnBlocks, TB, 0, stream>>>(xl, xr, csr, row_start, We1, att1, bi1, hbuf, N);

    // ---- layer 2 ----
    k_node_xf<<<nbXF, TB, 0, stream>>>(hbuf, 6, Wl2, bl2, Wr2, br2, xl, xr, N);
    k_attn<<<attnBlocks, TB, 0, stream>>>(xl, xr, csr, row_start, We2, att2, bi2, hbuf, N);

    // ---- pool + head ----
    hipMemsetAsync(pooled, 0, (size_t)G * 64 * 4, stream);
    hipMemsetAsync(gcnt, 0, (size_t)G * 4, stream);
    const int npw = 64;
    const int poolWaves = (N + npw - 1) / npw;
    k_pool2<<<(poolWaves * 64 + TB - 1) / TB, TB, 0, stream>>>(hbuf, batch, pooled, gcnt, N, npw);
    k_head<<<1, 64, 0, stream>>>(pooled, gcnt, Wf1, bf1, gam, bet, mu, var, Wf3, bf3,
                                 (float*)d_out, G);
}

// Round 14
// 369.726 us; speedup vs baseline: 1.0085x; 1.0085x over previous
//
#include <hip/hip_runtime.h>
#include <hip/hip_fp16.h>
#include <math.h>

typedef unsigned long long u64;
typedef __attribute__((ext_vector_type(2))) _Float16 half2v;
typedef __attribute__((ext_vector_type(4))) _Float16 half4v;

// ============================================================================
// CSR build = counting sort with coalesced writes. Edge record u32:
// [31:17] = fp16-bits-of-attr >> 1, [16:0] = src.
// Node transform v3: 64 nodes/block, 16 nodes/wave, ds_read_b128 row reads --
// 128 FMAs per 8 W-loads (L2 latency amortized). Fused with k_part (layer 1).
// Edge phase: round-12 form -- wave per dst, 16-lane x 4-edge packed fp16,
// unroll x2 (8 edges in flight).
// ============================================================================

#define MAXSPAN 12032   // max csr slots per bucket (mean ~8450)

// ---------- CSR build ----------

__global__ void k_hist(const int* __restrict__ ei, int* __restrict__ qcount,
                       int E, int epb) {
    __shared__ int h[256];
    int t = threadIdx.x;
    h[t] = 0;
    __syncthreads();
    int base = blockIdx.x * epb;
    int end = base + epb; if (end > E) end = E;
    for (int e = base + t; e < end; e += 256) {
        int d = ei[E + e];
        atomicAdd(&h[d >> 8], 1);
    }
    __syncthreads();
    int c = h[t];
    if (c) atomicAdd(&qcount[t], c);
}

// single block: scans + zeroes pool accumulators (folded memsets)
__global__ void k_bscan(const int* __restrict__ qcount, int* __restrict__ qbase,
                        int* __restrict__ qtail, int* __restrict__ csrbase,
                        int* __restrict__ row_start, int N, int E, int NB,
                        float* __restrict__ pooled, float* __restrict__ gcnt, int G) {
    __shared__ int s[256], s2[256];
    int t = threadIdx.x;
    for (int i = t; i < G * 64; i += 256) pooled[i] = 0.f;
    if (t < G) gcnt[t] = 0.f;
    int lo = t * 256;
    int ndst = (lo < N) ? ((N - lo < 256) ? (N - lo) : 256) : 0;
    int qc = (t < NB) ? qcount[t] : 0;
    s[t] = qc; s2[t] = qc + ndst;
    __syncthreads();
    for (int off = 1; off < 256; off <<= 1) {
        int a = (t >= off) ? s[t - off] : 0;
        int b = (t >= off) ? s2[t - off] : 0;
        __syncthreads();
        s[t] += a; s2[t] += b;
        __syncthreads();
    }
    if (t < NB) {
        qbase[t] = s[t] - qc;
        qtail[t] = s[t] - qc;
        csrbase[t] = s2[t] - (qc + ndst);
    }
    if (t == 255) {
        qbase[NB] = s[255];
        csrbase[NB] = s2[255];
        row_start[N] = s2[255];
    }
}

#define PEPB 4096   // edges per partition block

// ---------- node transform core: 64 nodes/block, 16 nodes/wave ----------
__device__ __forceinline__ void xf_block(
        const float* __restrict__ h, int ld,
        const float* __restrict__ Wl, const float* __restrict__ bl,
        const float* __restrict__ Wr, const float* __restrict__ br,
        __half* __restrict__ xl, __half* __restrict__ xr,
        int N, int node0, float* rows, int t) {
    int in_dim = 1 << ld;
    int q = in_dim >> 2;            // float4s per row
    for (int idx = t; idx < 64 * q; idx += 256) {
        int nn = idx >> (ld - 2);
        int kk = (idx & (q - 1)) << 2;
        int node = node0 + nn;
        float4 v = {0.f, 0.f, 0.f, 0.f};
        if (node < N) v = *(const float4*)(h + (((size_t)node) << ld) + kk);
        *(float4*)(rows + (nn << ld) + kk) = v;
    }
    __syncthreads();
    int lane = t & 63, w = t >> 6;
    int nb = w * 16;
    float al[16], ar[16];
    float blv = bl[lane], brv = br[lane];
#pragma unroll
    for (int i = 0; i < 16; ++i) { al[i] = blv; ar[i] = brv; }
    for (int k = 0; k < in_dim; k += 4) {
        float wl0 = Wl[(k + 0) * 64 + lane], wl1 = Wl[(k + 1) * 64 + lane];
        float wl2 = Wl[(k + 2) * 64 + lane], wl3 = Wl[(k + 3) * 64 + lane];
        float wr0 = Wr[(k + 0) * 64 + lane], wr1 = Wr[(k + 1) * 64 + lane];
        float wr2 = Wr[(k + 2) * 64 + lane], wr3 = Wr[(k + 3) * 64 + lane];
#pragma unroll
        for (int i = 0; i < 16; ++i) {
            float4 r = *(const float4*)(rows + ((nb + i) << ld) + k);
            al[i] = fmaf(r.x, wl0, al[i]); al[i] = fmaf(r.y, wl1, al[i]);
            al[i] = fmaf(r.z, wl2, al[i]); al[i] = fmaf(r.w, wl3, al[i]);
            ar[i] = fmaf(r.x, wr0, ar[i]); ar[i] = fmaf(r.y, wr1, ar[i]);
            ar[i] = fmaf(r.z, wr2, ar[i]); ar[i] = fmaf(r.w, wr3, ar[i]);
        }
    }
#pragma unroll
    for (int i = 0; i < 16; ++i) {
        int node = node0 + nb + i;
        if (node < N) {
            xl[((size_t)node << 6) + lane] = __float2half(al[i]);
            xr[((size_t)node << 6) + lane] = __float2half(ar[i]);
        }
    }
}

// FUSED: blocks [0,nbXF) = layer-1 node transform; blocks [nbXF,..) = k_part
__global__ void k_xf1_part(
        const float* __restrict__ h, int ld,
        const float* __restrict__ Wl, const float* __restrict__ bl,
        const float* __restrict__ Wr, const float* __restrict__ br,
        __half* __restrict__ xl, __half* __restrict__ xr, int N, int nbXF,
        const int* __restrict__ ei, const float* __restrict__ ea,
        int* __restrict__ qtail, u64* __restrict__ queue, int E) {
    __shared__ float rows[8192];   // 64 x up-to-128
    __shared__ int lh[256], lbase[256], lcur[256];
    int t = threadIdx.x;
    if (blockIdx.x < nbXF) {
        xf_block(h, ld, Wl, bl, Wr, br, xl, xr, N, blockIdx.x * 64, rows, t);
    } else {
        int pb = blockIdx.x - nbXF;
        lh[t] = 0; lcur[t] = 0;
        __syncthreads();
        int base = pb * PEPB;
        int end = base + PEPB; if (end > E) end = E;
        int dreg[PEPB / 256];
#pragma unroll
        for (int k = 0; k < PEPB / 256; ++k) {
            int e = base + t + k * 256;
            if (e < end) {
                dreg[k] = ei[E + e];
                atomicAdd(&lh[dreg[k] >> 8], 1);
            }
        }
        __syncthreads();
        if (lh[t]) lbase[t] = atomicAdd(&qtail[t], lh[t]);
        __syncthreads();
#pragma unroll
        for (int k = 0; k < PEPB / 256; ++k) {
            int e = base + t + k * 256;
            if (e < end) {
                int d = dreg[k];
                int src = ei[e];
                float a = ea[e];
                int b = d >> 8;
                int idx = atomicAdd(&lcur[b], 1);
                unsigned aq = (unsigned)(a * 16777216.0f);    // fixed-24, attr in [0,1)
                queue[lbase[b] + idx] = (((u64)aq) << 25) | (((u64)(d & 255)) << 17) | (unsigned)src;
            }
        }
    }
}

__device__ __forceinline__ unsigned attr_q15(float a) {
    unsigned short hb = __builtin_bit_cast(unsigned short, (_Float16)a);
    return (unsigned)(hb >> 1);       // attr in [0,1) -> fp16 top bit 0
}

// 1024 threads (16 waves) per bucket
__global__ void __launch_bounds__(1024)
k_build(const u64* __restrict__ queue, const int* __restrict__ qbase,
        const int* __restrict__ csrbase,
        int* __restrict__ row_start, unsigned* __restrict__ csr, int N) {
    __shared__ u64 stat[256];
    __shared__ int fill[256], sc[256];
    __shared__ unsigned lcsr[MAXSPAN];
    int t = threadIdx.x, b = blockIdx.x;
    if (t < 256) stat[t] = 0;
    __syncthreads();
    int q0 = qbase[b], q1 = qbase[b + 1];
    for (int i = q0 + t; i < q1; i += 1024) {
        u64 r = queue[i];
        int dl = (int)((r >> 17) & 255);
        atomicAdd(&stat[dl], (1ULL << 32) | (unsigned)(r >> 25));
    }
    __syncthreads();
    int dg = b * 256 + t;
    u64 p = (t < 256) ? stat[t] : 0;
    int deg = (int)(p >> 32);
    int v = (t < 256 && dg < N) ? deg + 1 : 0;
    if (t < 256) sc[t] = v;
    __syncthreads();
    for (int off = 1; off < 256; off <<= 1) {
        int a = (t >= off && t < 256) ? sc[t - off] : 0;
        __syncthreads();
        if (t < 256) sc[t] += a;
        __syncthreads();
    }
    if (t < 256 && dg < N) {
        int basel = sc[t] - v;   // exclusive
        row_start[dg] = csrbase[b] + basel;
        fill[t] = basel;
        float mean = ((float)(unsigned)p * (1.0f / 16777216.0f)) / fmaxf((float)deg, 1.0f);
        if (basel + deg < MAXSPAN) lcsr[basel + deg] = (attr_q15(mean) << 17) | (unsigned)dg;
    }
    __syncthreads();
    for (int i = q0 + t; i < q1; i += 1024) {
        u64 r = queue[i];
        int dl = (int)((r >> 17) & 255);
        int pos = atomicAdd(&fill[dl], 1);
        float av = (float)(unsigned)(r >> 25) * (1.0f / 16777216.0f);
        if (pos < MAXSPAN) lcsr[pos] = (attr_q15(av) << 17) | (unsigned)(r & 0x1FFFFu);
    }
    __syncthreads();
    int c0 = csrbase[b], span = csrbase[b + 1] - c0;
    if (span > MAXSPAN) span = MAXSPAN;
    for (int j = t; j < span; j += 1024) csr[c0 + j] = lcsr[j];
}

// ---------- node transform (standalone, layer 2) ----------
__global__ void k_node_xf(const float* __restrict__ h, int ld,
                          const float* __restrict__ Wl, const float* __restrict__ bl,
                          const float* __restrict__ Wr, const float* __restrict__ br,
                          __half* __restrict__ xl, __half* __restrict__ xr, int N) {
    __shared__ float rows[8192];
    xf_block(h, ld, Wl, bl, Wr, br, xl, xr, N, blockIdx.x * 64, rows, threadIdx.x);
}

// ---------- fused edge phase: wave/dst, 16x4 packed fp16, unroll x2 ----------
__global__ void k_attn(const __half* __restrict__ xl, const __half* __restrict__ xr,
                       const unsigned* __restrict__ csr, const int* __restrict__ row_start,
                       const float* __restrict__ We, const float* __restrict__ att,
                       const float* __restrict__ bias,
                       float* __restrict__ hout, int N) {
    int lane = threadIdx.x & 63;
    int d = (int)(((size_t)blockIdx.x * blockDim.x + threadIdx.x) >> 6);
    if (d >= N) return;
    int eq = lane >> 4;           // which of 4 concurrent edges
    int fl = lane & 15;           // which 4-dim chunk of the 64 dims
    float4 Wef  = *(const float4*)(We + fl * 4);
    float4 attf = *(const float4*)(att + fl * 4);
    half2v We01 = {(_Float16)Wef.x, (_Float16)Wef.y};
    half2v We23 = {(_Float16)Wef.z, (_Float16)Wef.w};
    half2v at01 = {(_Float16)attf.x, (_Float16)attf.y};
    half2v at23 = {(_Float16)attf.z, (_Float16)attf.w};
    half4v xrh = *(const half4v*)(xr + ((size_t)d << 6) + fl * 4);
    half2v xr01 = {xrh.x, xrh.y}, xr23 = {xrh.z, xrh.w};
    const half2v k02 = {(_Float16)0.2f, (_Float16)0.2f};
    int e0 = __builtin_amdgcn_readfirstlane(row_start[d]);
    int e1 = __builtin_amdgcn_readfirstlane(row_start[d + 1]);
    float l = 0.f;
    float4 O = {0.f, 0.f, 0.f, 0.f};
    int e = e0;
    for (; e + 8 <= e1; e += 8) {       // 8 edges in flight
        unsigned rA = csr[e + eq];
        unsigned rB = csr[e + 4 + eq];
        half4v xA = *(const half4v*)(xl + (((size_t)(rA & 0x1FFFFu)) << 6) + fl * 4);
        half4v xB = *(const half4v*)(xl + (((size_t)(rB & 0x1FFFFu)) << 6) + fl * 4);
        _Float16 ahA = __builtin_bit_cast(_Float16, (unsigned short)((rA >> 16) & 0xFFFEu));
        _Float16 ahB = __builtin_bit_cast(_Float16, (unsigned short)((rB >> 16) & 0xFFFEu));
        half2v aaA = {ahA, ahA}, aaB = {ahB, ahB};
        half2v xA01 = {xA.x, xA.y}, xA23 = {xA.z, xA.w};
        half2v xB01 = {xB.x, xB.y}, xB23 = {xB.z, xB.w};
        half2v vA01 = aaA * We01 + (xA01 + xr01);
        half2v vA23 = aaA * We23 + (xA23 + xr23);
        half2v vB01 = aaB * We01 + (xB01 + xr01);
        half2v vB23 = aaB * We23 + (xB23 + xr23);
        half2v sA01 = __builtin_elementwise_max(vA01, vA01 * k02);
        half2v sA23 = __builtin_elementwise_max(vA23, vA23 * k02);
        half2v sB01 = __builtin_elementwise_max(vB01, vB01 * k02);
        half2v sB23 = __builtin_elementwise_max(vB23, vB23 * k02);
#if __has_builtin(__builtin_amdgcn_fdot2)
        float cA = __builtin_amdgcn_fdot2(sA01, at01, 0.f, false);
        cA = __builtin_amdgcn_fdot2(sA23, at23, cA, false);
        float cB = __builtin_amdgcn_fdot2(sB01, at01, 0.f, false);
        cB = __builtin_amdgcn_fdot2(sB23, at23, cB, false);
#else
        float cA = (float)sA01.x * (float)at01.x + (float)sA01.y * (float)at01.y
                 + (float)sA23.x * (float)at23.x + (float)sA23.y * (float)at23.y;
        float cB = (float)sB01.x * (float)at01.x + (float)sB01.y * (float)at01.y
                 + (float)sB23.x * (float)at23.x + (float)sB23.y * (float)at23.y;
#endif
#pragma unroll
        for (int mm = 1; mm <= 8; mm <<= 1) {
            cA += __shfl_xor(cA, mm, 64);
            cB += __shfl_xor(cB, mm, 64);
        }
        float qA = __expf(cA), qB = __expf(cB);
        l += qA + qB;
        O.x = fmaf(qA, (float)xA.x, O.x); O.x = fmaf(qB, (float)xB.x, O.x);
        O.y = fmaf(qA, (float)xA.y, O.y); O.y = fmaf(qB, (float)xB.y, O.y);
        O.z = fmaf(qA, (float)xA.z, O.z); O.z = fmaf(qB, (float)xB.z, O.z);
        O.w = fmaf(qA, (float)xA.w, O.w); O.w = fmaf(qB, (float)xB.w, O.w);
    }
    for (; e < e1; e += 4) {            // tail with clamp
        int ee = e + eq;
        bool valid = ee < e1;
        unsigned r = csr[valid ? ee : (e1 - 1)];
        _Float16 ah = __builtin_bit_cast(_Float16, (unsigned short)((r >> 16) & 0xFFFEu));
        half2v aa = {ah, ah};
        half4v xh = *(const half4v*)(xl + (((size_t)(r & 0x1FFFFu)) << 6) + fl * 4);
        half2v x01 = {xh.x, xh.y}, x23 = {xh.z, xh.w};
        half2v v01 = aa * We01 + (x01 + xr01);
        half2v v23 = aa * We23 + (x23 + xr23);
        half2v s01 = __builtin_elementwise_max(v01, v01 * k02);
        half2v s23 = __builtin_elementwise_max(v23, v23 * k02);
#if __has_builtin(__builtin_amdgcn_fdot2)
        float c = __builtin_amdgcn_fdot2(s01, at01, 0.f, false);
        c = __builtin_amdgcn_fdot2(s23, at23, c, false);
#else
        float c = (float)s01.x * (float)at01.x + (float)s01.y * (float)at01.y
                + (float)s23.x * (float)at23.x + (float)s23.y * (float)at23.y;
#endif
#pragma unroll
        for (int mm = 1; mm <= 8; mm <<= 1) c += __shfl_xor(c, mm, 64);
        float q = valid ? __expf(c) : 0.f;
        l += q;
        O.x = fmaf(q, (float)xh.x, O.x);
        O.y = fmaf(q, (float)xh.y, O.y);
        O.z = fmaf(q, (float)xh.z, O.z);
        O.w = fmaf(q, (float)xh.w, O.w);
    }
#pragma unroll
    for (int mm = 16; mm <= 32; mm <<= 1) {
        l   += __shfl_xor(l, mm, 64);
        O.x += __shfl_xor(O.x, mm, 64);
        O.y += __shfl_xor(O.y, mm, 64);
        O.z += __shfl_xor(O.z, mm, 64);
        O.w += __shfl_xor(O.w, mm, 64);
    }
    if (eq == 0) {
        float inv = 1.0f / (l + 1e-16f);
        float4 b4 = *(const float4*)(bias + fl * 4);
        float4 res;
        res.x = fmaf(O.x, inv, b4.x);
        res.y = fmaf(O.y, inv, b4.y);
        res.z = fmaf(O.z, inv, b4.z);
        res.w = fmaf(O.w, inv, b4.w);
        res.x = res.x > 0.f ? res.x : expm1f(res.x);
        res.y = res.y > 0.f ? res.y : expm1f(res.y);
        res.z = res.z > 0.f ? res.z : expm1f(res.z);
        res.w = res.w > 0.f ? res.w : expm1f(res.w);
        *(float4*)(hout + ((size_t)d << 6) + fl * 4) = res;
    }
}

// ---------- pool: batch sorted -> run-length accumulate ----------
__global__ void k_pool2(const float* __restrict__ h, const int* __restrict__ batch,
                        float* __restrict__ pooled, float* __restrict__ gcnt,
                        int N, int npw) {
    int lane = threadIdx.x & 63;
    int wave = (int)(((size_t)blockIdx.x * blockDim.x + threadIdx.x) >> 6);
    int begin = wave * npw;
    if (begin >= N) return;
    int end = begin + npw; if (end > N) end = N;
    int g = batch[begin];
    float acc = 0.f, cnt = 0.f;
    for (int n = begin; n < end; ++n) {
        int gn = batch[n];
        if (gn != g) {
            atomicAdd(&pooled[((size_t)g << 6) + lane], acc);
            if (lane == 0) atomicAdd(&gcnt[g], cnt);
            g = gn; acc = 0.f; cnt = 0.f;
        }
        acc += h[((size_t)n << 6) + lane];
        cnt += 1.f;
    }
    atomicAdd(&pooled[((size_t)g << 6) + lane], acc);
    if (lane == 0) atomicAdd(&gcnt[g], cnt);
}

// ---------- MLP head ----------
__global__ void k_head(const float* __restrict__ pooled, const float* __restrict__ gcnt,
                       const float* __restrict__ W1, const float* __restrict__ b1,
                       const float* __restrict__ gam, const float* __restrict__ bet,
                       const float* __restrict__ mu, const float* __restrict__ var,
                       const float* __restrict__ W3, const float* __restrict__ b3,
                       float* __restrict__ out, int G) {
    int g = blockIdx.x * blockDim.x + threadIdx.x;
    if (g >= G) return;
    float inv = 1.0f / fmaxf(gcnt[g], 1.0f);
    float pr[64];
    for (int k = 0; k < 64; ++k) pr[k] = pooled[((size_t)g << 6) + k] * inv;
    float o = b3[0];
    for (int j = 0; j < 32; ++j) {
        float z = b1[j];
        for (int k = 0; k < 64; ++k) z += pr[k] * W1[k * 32 + j];
        z = fmaxf(z, 0.f);
        z = (z - mu[j]) / sqrtf(var[j] + 1e-5f) * gam[j] + bet[j];
        o += z * W3[j];
    }
    out[g] = o;
}

// ---------- launch ----------
extern "C" void kernel_launch(void* const* d_in, const int* in_sizes, int n_in,
                              void* d_out, int out_size, void* d_ws, size_t ws_size,
                              hipStream_t stream) {
    const float* x    = (const float*)d_in[0];
    const int*   ei   = (const int*)d_in[1];
    const float* ea   = (const float*)d_in[2];
    const int*   batch= (const int*)d_in[3];
    const float* Wl1  = (const float*)d_in[4];
    const float* bl1  = (const float*)d_in[5];
    const float* Wr1  = (const float*)d_in[6];
    const float* br1  = (const float*)d_in[7];
    const float* We1  = (const float*)d_in[8];
    const float* att1 = (const float*)d_in[9];
    const float* bi1  = (const float*)d_in[10];
    const float* Wl2  = (const float*)d_in[11];
    const float* bl2  = (const float*)d_in[12];
    const float* Wr2  = (const float*)d_in[13];
    const float* br2  = (const float*)d_in[14];
    const float* We2  = (const float*)d_in[15];
    const float* att2 = (const float*)d_in[16];
    const float* bi2  = (const float*)d_in[17];
    const float* Wf1  = (const float*)d_in[18];
    const float* bf1  = (const float*)d_in[19];
    const float* gam  = (const float*)d_in[20];
    const float* bet  = (const float*)d_in[21];
    const float* mu   = (const float*)d_in[22];
    const float* var  = (const float*)d_in[23];
    const float* Wf3  = (const float*)d_in[24];
    const float* bf3  = (const float*)d_in[25];

    const int N    = in_sizes[3];          // 50000
    const int E    = in_sizes[2];          // 1600000
    const int INd  = in_sizes[0] / N;      // 128
    const int ld1  = (INd == 128) ? 7 : 6;
    const int Etot = E + N;
    const int G    = out_size;             // 64
    const int NB   = (N + 255) / 256;      // buckets (<=256)

    // workspace carve-up (256B aligned)
    char* w = (char*)d_ws;
    auto carve = [&](size_t bytes) { char* p = w; w += (bytes + 255) & ~(size_t)255; return p; };
    __half*   xl       = (__half*)  carve((size_t)N * 64 * 2);
    __half*   xr       = (__half*)  carve((size_t)N * 64 * 2);
    float*    hbuf     = (float*)   carve((size_t)N * 64 * 4);
    unsigned* csr      = (unsigned*)carve((size_t)(Etot + 8) * 4);
    u64*      queue    = (u64*)     carve((size_t)E * 8);
    int*      row_start= (int*)     carve((size_t)(N + 1) * 4);
    int*      qcount   = (int*)     carve((size_t)256 * 4);
    int*      qbase    = (int*)     carve((size_t)257 * 4);
    int*      qtail    = (int*)     carve((size_t)256 * 4);
    int*      csrbase  = (int*)     carve((size_t)257 * 4);
    float*    pooled   = (float*)   carve((size_t)G * 64 * 4);
    float*    gcnt     = (float*)   carve((size_t)G * 4);

    const int TB = 256;
    const int nbXF = (N + 63) / 64;              // node-transform blocks (64 nodes)
    const int attnBlocks = (N + 3) / 4;          // wave per dst, 4 waves/block

    // ---- CSR build start ----
    hipMemsetAsync(qcount, 0, 256 * 4, stream);
    const int hepb = 8192;
    k_hist<<<(E + hepb - 1) / hepb, TB, 0, stream>>>(ei, qcount, E, hepb);
    k_bscan<<<1, 256, 0, stream>>>(qcount, qbase, qtail, csrbase, row_start, N, E, NB,
                                   pooled, gcnt, G);
    // ---- fused: layer-1 node transform || edge partition ----
    const int nbPart = (E + PEPB - 1) / PEPB;
    k_xf1_part<<<nbXF + nbPart, TB, 0, stream>>>(x, ld1, Wl1, bl1, Wr1, br1, xl, xr, N, nbXF,
                                                 ei, ea, qtail, queue, E);
    k_build<<<NB, 1024, 0, stream>>>(queue, qbase, csrbase, row_start, csr, N);

    // ---- layer 1 edge phase ----
    k_attn<<<attnBlocks, TB, 0, stream>>>(xl, xr, csr, row_start, We1, att1, bi1, hbuf, N);

    // ---- layer 2 ----
    k_node_xf<<<nbXF, TB, 0, stream>>>(hbuf, 6, Wl2, bl2, Wr2, br2, xl, xr, N);
    k_attn<<<attnBlocks, TB, 0, stream>>>(xl, xr, csr, row_start, We2, att2, bi2, hbuf, N);

    // ---- pool + head ----
    const int npw = 64;
    const int poolWaves = (N + npw - 1) / npw;
    k_pool2<<<(poolWaves * 64 + TB - 1) / TB, TB, 0, stream>>>(hbuf, batch, pooled, gcnt, N, npw);
    k_head<<<1, 64, 0, stream>>>(pooled, gcnt, Wf1, bf1, gam, bet, mu, var, Wf3, bf3,
                                 (float*)d_out, G);
}

// Round 15
// 369.397 us; speedup vs baseline: 1.0094x; 1.0009x over previous
//
#include <hip/hip_runtime.h>
#include <hip/hip_fp16.h>
#include <math.h>

typedef unsigned long long u64;
typedef __attribute__((ext_vector_type(2))) _Float16 half2v;
typedef __attribute__((ext_vector_type(4))) _Float16 half4v;

// ============================================================================
// CSR build = counting sort with coalesced writes. Edge record u32:
// [31:17] = fp16-bits-of-attr >> 1, [16:0] = src.
// Node transform: 64 nodes/block, 16 nodes/wave, rows staged in LDS as fp16
// (v_fma_mix fp32 accumulate); shared mem UNIONed with partition arrays ->
// 16 KB/block, ~9 blocks/CU (round-14 had 35.8 KB -> 4 blocks/CU, occ 32%).
// Edge phase: wave per dst, 16-lane x 4-edge packed fp16, unroll x2.
// Head fused into pool via last-block-done counter.
// ============================================================================

#define MAXSPAN 12032   // max csr slots per bucket (mean ~8450)

// ---------- CSR build ----------

__global__ void k_hist(const int* __restrict__ ei, int* __restrict__ qcount,
                       int E, int epb) {
    __shared__ int h[256];
    int t = threadIdx.x;
    h[t] = 0;
    __syncthreads();
    int base = blockIdx.x * epb;
    int end = base + epb; if (end > E) end = E;
    for (int e = base + t; e < end; e += 256) {
        int d = ei[E + e];
        atomicAdd(&h[d >> 8], 1);
    }
    __syncthreads();
    int c = h[t];
    if (c) atomicAdd(&qcount[t], c);
}

// single block: scans + zeroes pool accumulators and the done counter
__global__ void k_bscan(const int* __restrict__ qcount, int* __restrict__ qbase,
                        int* __restrict__ qtail, int* __restrict__ csrbase,
                        int* __restrict__ row_start, int N, int E, int NB,
                        float* __restrict__ pooled, float* __restrict__ gcnt,
                        int* __restrict__ done, int G) {
    __shared__ int s[256], s2[256];
    int t = threadIdx.x;
    for (int i = t; i < G * 64; i += 256) pooled[i] = 0.f;
    if (t < G) gcnt[t] = 0.f;
    if (t == 0) *done = 0;
    int lo = t * 256;
    int ndst = (lo < N) ? ((N - lo < 256) ? (N - lo) : 256) : 0;
    int qc = (t < NB) ? qcount[t] : 0;
    s[t] = qc; s2[t] = qc + ndst;
    __syncthreads();
    for (int off = 1; off < 256; off <<= 1) {
        int a = (t >= off) ? s[t - off] : 0;
        int b = (t >= off) ? s2[t - off] : 0;
        __syncthreads();
        s[t] += a; s2[t] += b;
        __syncthreads();
    }
    if (t < NB) {
        qbase[t] = s[t] - qc;
        qtail[t] = s[t] - qc;
        csrbase[t] = s2[t] - (qc + ndst);
    }
    if (t == 255) {
        qbase[NB] = s[255];
        csrbase[NB] = s2[255];
        row_start[N] = s2[255];
    }
}

#define PEPB 4096   // edges per partition block

// ---------- node transform core: 64 nodes/block, 16 nodes/wave, fp16 rows ----------
__device__ __forceinline__ void xf_block(
        const float* __restrict__ h, int ld,
        const float* __restrict__ Wl, const float* __restrict__ bl,
        const float* __restrict__ Wr, const float* __restrict__ br,
        __half* __restrict__ xl, __half* __restrict__ xr,
        int N, int node0, _Float16* rows, int t) {
    int in_dim = 1 << ld;
    int q = in_dim >> 2;            // 4-element chunks per row
    for (int idx = t; idx < 64 * q; idx += 256) {
        int nn = idx >> (ld - 2);
        int kk = (idx & (q - 1)) << 2;
        int node = node0 + nn;
        float4 v = {0.f, 0.f, 0.f, 0.f};
        if (node < N) v = *(const float4*)(h + (((size_t)node) << ld) + kk);
        half4v hv = {(_Float16)v.x, (_Float16)v.y, (_Float16)v.z, (_Float16)v.w};
        *(half4v*)(rows + (nn << ld) + kk) = hv;
    }
    __syncthreads();
    int lane = t & 63, w = t >> 6;
    int nb = w * 16;
    float al[16], ar[16];
    float blv = bl[lane], brv = br[lane];
#pragma unroll
    for (int i = 0; i < 16; ++i) { al[i] = blv; ar[i] = brv; }
    for (int k = 0; k < in_dim; k += 4) {
        float wl0 = Wl[(k + 0) * 64 + lane], wl1 = Wl[(k + 1) * 64 + lane];
        float wl2 = Wl[(k + 2) * 64 + lane], wl3 = Wl[(k + 3) * 64 + lane];
        float wr0 = Wr[(k + 0) * 64 + lane], wr1 = Wr[(k + 1) * 64 + lane];
        float wr2 = Wr[(k + 2) * 64 + lane], wr3 = Wr[(k + 3) * 64 + lane];
#pragma unroll
        for (int i = 0; i < 16; ++i) {
            half4v r = *(const half4v*)(rows + ((nb + i) << ld) + k);  // broadcast
            al[i] = fmaf((float)r.x, wl0, al[i]); al[i] = fmaf((float)r.y, wl1, al[i]);
            al[i] = fmaf((float)r.z, wl2, al[i]); al[i] = fmaf((float)r.w, wl3, al[i]);
            ar[i] = fmaf((float)r.x, wr0, ar[i]); ar[i] = fmaf((float)r.y, wr1, ar[i]);
            ar[i] = fmaf((float)r.z, wr2, ar[i]); ar[i] = fmaf((float)r.w, wr3, ar[i]);
        }
    }
#pragma unroll
    for (int i = 0; i < 16; ++i) {
        int node = node0 + nb + i;
        if (node < N) {
            xl[((size_t)node << 6) + lane] = __float2half(al[i]);
            xr[((size_t)node << 6) + lane] = __float2half(ar[i]);
        }
    }
}

// shared-memory union: xf rows (16 KB max) vs partition arrays (3 KB)
union XfPartSmem {
    _Float16 rows[64 * 128];
    struct { int lh[256]; int lbase[256]; int lcur[256]; } p;
};

// FUSED: blocks [0,nbXF) = layer-1 node transform; blocks [nbXF,..) = k_part
__global__ void k_xf1_part(
        const float* __restrict__ h, int ld,
        const float* __restrict__ Wl, const float* __restrict__ bl,
        const float* __restrict__ Wr, const float* __restrict__ br,
        __half* __restrict__ xl, __half* __restrict__ xr, int N, int nbXF,
        const int* __restrict__ ei, const float* __restrict__ ea,
        int* __restrict__ qtail, u64* __restrict__ queue, int E) {
    __shared__ XfPartSmem sm;
    int t = threadIdx.x;
    if (blockIdx.x < nbXF) {
        xf_block(h, ld, Wl, bl, Wr, br, xl, xr, N, blockIdx.x * 64, sm.rows, t);
    } else {
        int pb = blockIdx.x - nbXF;
        sm.p.lh[t] = 0; sm.p.lcur[t] = 0;
        __syncthreads();
        int base = pb * PEPB;
        int end = base + PEPB; if (end > E) end = E;
        int dreg[PEPB / 256];
#pragma unroll
        for (int k = 0; k < PEPB / 256; ++k) {
            int e = base + t + k * 256;
            if (e < end) {
                dreg[k] = ei[E + e];
                atomicAdd(&sm.p.lh[dreg[k] >> 8], 1);
            }
        }
        __syncthreads();
        if (sm.p.lh[t]) sm.p.lbase[t] = atomicAdd(&qtail[t], sm.p.lh[t]);
        __syncthreads();
#pragma unroll
        for (int k = 0; k < PEPB / 256; ++k) {
            int e = base + t + k * 256;
            if (e < end) {
                int d = dreg[k];
                int src = ei[e];
                float a = ea[e];
                int b = d >> 8;
                int idx = atomicAdd(&sm.p.lcur[b], 1);
                unsigned aq = (unsigned)(a * 16777216.0f);    // fixed-24, attr in [0,1)
                queue[sm.p.lbase[b] + idx] = (((u64)aq) << 25) | (((u64)(d & 255)) << 17) | (unsigned)src;
            }
        }
    }
}

__device__ __forceinline__ unsigned attr_q15(float a) {
    unsigned short hb = __builtin_bit_cast(unsigned short, (_Float16)a);
    return (unsigned)(hb >> 1);       // attr in [0,1) -> fp16 top bit 0
}

// 1024 threads (16 waves) per bucket
__global__ void __launch_bounds__(1024)
k_build(const u64* __restrict__ queue, const int* __restrict__ qbase,
        const int* __restrict__ csrbase,
        int* __restrict__ row_start, unsigned* __restrict__ csr, int N) {
    __shared__ u64 stat[256];
    __shared__ int fill[256], sc[256];
    __shared__ unsigned lcsr[MAXSPAN];
    int t = threadIdx.x, b = blockIdx.x;
    if (t < 256) stat[t] = 0;
    __syncthreads();
    int q0 = qbase[b], q1 = qbase[b + 1];
    for (int i = q0 + t; i < q1; i += 1024) {
        u64 r = queue[i];
        int dl = (int)((r >> 17) & 255);
        atomicAdd(&stat[dl], (1ULL << 32) | (unsigned)(r >> 25));
    }
    __syncthreads();
    int dg = b * 256 + t;
    u64 p = (t < 256) ? stat[t] : 0;
    int deg = (int)(p >> 32);
    int v = (t < 256 && dg < N) ? deg + 1 : 0;
    if (t < 256) sc[t] = v;
    __syncthreads();
    for (int off = 1; off < 256; off <<= 1) {
        int a = (t >= off && t < 256) ? sc[t - off] : 0;
        __syncthreads();
        if (t < 256) sc[t] += a;
        __syncthreads();
    }
    if (t < 256 && dg < N) {
        int basel = sc[t] - v;   // exclusive
        row_start[dg] = csrbase[b] + basel;
        fill[t] = basel;
        float mean = ((float)(unsigned)p * (1.0f / 16777216.0f)) / fmaxf((float)deg, 1.0f);
        if (basel + deg < MAXSPAN) lcsr[basel + deg] = (attr_q15(mean) << 17) | (unsigned)dg;
    }
    __syncthreads();
    for (int i = q0 + t; i < q1; i += 1024) {
        u64 r = queue[i];
        int dl = (int)((r >> 17) & 255);
        int pos = atomicAdd(&fill[dl], 1);
        float av = (float)(unsigned)(r >> 25) * (1.0f / 16777216.0f);
        if (pos < MAXSPAN) lcsr[pos] = (attr_q15(av) << 17) | (unsigned)(r & 0x1FFFFu);
    }
    __syncthreads();
    int c0 = csrbase[b], span = csrbase[b + 1] - c0;
    if (span > MAXSPAN) span = MAXSPAN;
    for (int j = t; j < span; j += 1024) csr[c0 + j] = lcsr[j];
}

// ---------- node transform (standalone, layer 2: ld=6 -> 8 KB rows) ----------
__global__ void k_node_xf(const float* __restrict__ h, int ld,
                          const float* __restrict__ Wl, const float* __restrict__ bl,
                          const float* __restrict__ Wr, const float* __restrict__ br,
                          __half* __restrict__ xl, __half* __restrict__ xr, int N) {
    __shared__ _Float16 rows[64 * 64];
    xf_block(h, ld, Wl, bl, Wr, br, xl, xr, N, blockIdx.x * 64, rows, threadIdx.x);
}

// ---------- fused edge phase: wave/dst, 16x4 packed fp16, unroll x2 ----------
__global__ void k_attn(const __half* __restrict__ xl, const __half* __restrict__ xr,
                       const unsigned* __restrict__ csr, const int* __restrict__ row_start,
                       const float* __restrict__ We, const float* __restrict__ att,
                       const float* __restrict__ bias,
                       float* __restrict__ hout, int N) {
    int lane = threadIdx.x & 63;
    int d = (int)(((size_t)blockIdx.x * blockDim.x + threadIdx.x) >> 6);
    if (d >= N) return;
    int eq = lane >> 4;           // which of 4 concurrent edges
    int fl = lane & 15;           // which 4-dim chunk of the 64 dims
    float4 Wef  = *(const float4*)(We + fl * 4);
    float4 attf = *(const float4*)(att + fl * 4);
    half2v We01 = {(_Float16)Wef.x, (_Float16)Wef.y};
    half2v We23 = {(_Float16)Wef.z, (_Float16)Wef.w};
    half2v at01 = {(_Float16)attf.x, (_Float16)attf.y};
    half2v at23 = {(_Float16)attf.z, (_Float16)attf.w};
    half4v xrh = *(const half4v*)(xr + ((size_t)d << 6) + fl * 4);
    half2v xr01 = {xrh.x, xrh.y}, xr23 = {xrh.z, xrh.w};
    const half2v k02 = {(_Float16)0.2f, (_Float16)0.2f};
    int e0 = __builtin_amdgcn_readfirstlane(row_start[d]);
    int e1 = __builtin_amdgcn_readfirstlane(row_start[d + 1]);
    float l = 0.f;
    float4 O = {0.f, 0.f, 0.f, 0.f};
    int e = e0;
    for (; e + 8 <= e1; e += 8) {       // 8 edges in flight
        unsigned rA = csr[e + eq];
        unsigned rB = csr[e + 4 + eq];
        half4v xA = *(const half4v*)(xl + (((size_t)(rA & 0x1FFFFu)) << 6) + fl * 4);
        half4v xB = *(const half4v*)(xl + (((size_t)(rB & 0x1FFFFu)) << 6) + fl * 4);
        _Float16 ahA = __builtin_bit_cast(_Float16, (unsigned short)((rA >> 16) & 0xFFFEu));
        _Float16 ahB = __builtin_bit_cast(_Float16, (unsigned short)((rB >> 16) & 0xFFFEu));
        half2v aaA = {ahA, ahA}, aaB = {ahB, ahB};
        half2v xA01 = {xA.x, xA.y}, xA23 = {xA.z, xA.w};
        half2v xB01 = {xB.x, xB.y}, xB23 = {xB.z, xB.w};
        half2v vA01 = aaA * We01 + (xA01 + xr01);
        half2v vA23 = aaA * We23 + (xA23 + xr23);
        half2v vB01 = aaB * We01 + (xB01 + xr01);
        half2v vB23 = aaB * We23 + (xB23 + xr23);
        half2v sA01 = __builtin_elementwise_max(vA01, vA01 * k02);
        half2v sA23 = __builtin_elementwise_max(vA23, vA23 * k02);
        half2v sB01 = __builtin_elementwise_max(vB01, vB01 * k02);
        half2v sB23 = __builtin_elementwise_max(vB23, vB23 * k02);
#if __has_builtin(__builtin_amdgcn_fdot2)
        float cA = __builtin_amdgcn_fdot2(sA01, at01, 0.f, false);
        cA = __builtin_amdgcn_fdot2(sA23, at23, cA, false);
        float cB = __builtin_amdgcn_fdot2(sB01, at01, 0.f, false);
        cB = __builtin_amdgcn_fdot2(sB23, at23, cB, false);
#else
        float cA = (float)sA01.x * (float)at01.x + (float)sA01.y * (float)at01.y
                 + (float)sA23.x * (float)at23.x + (float)sA23.y * (float)at23.y;
        float cB = (float)sB01.x * (float)at01.x + (float)sB01.y * (float)at01.y
                 + (float)sB23.x * (float)at23.x + (float)sB23.y * (float)at23.y;
#endif
#pragma unroll
        for (int mm = 1; mm <= 8; mm <<= 1) {
            cA += __shfl_xor(cA, mm, 64);
            cB += __shfl_xor(cB, mm, 64);
        }
        float qA = __expf(cA), qB = __expf(cB);
        l += qA + qB;
        O.x = fmaf(qA, (float)xA.x, O.x); O.x = fmaf(qB, (float)xB.x, O.x);
        O.y = fmaf(qA, (float)xA.y, O.y); O.y = fmaf(qB, (float)xB.y, O.y);
        O.z = fmaf(qA, (float)xA.z, O.z); O.z = fmaf(qB, (float)xB.z, O.z);
        O.w = fmaf(qA, (float)xA.w, O.w); O.w = fmaf(qB, (float)xB.w, O.w);
    }
    for (; e < e1; e += 4) {            // tail with clamp
        int ee = e + eq;
        bool valid = ee < e1;
        unsigned r = csr[valid ? ee : (e1 - 1)];
        _Float16 ah = __builtin_bit_cast(_Float16, (unsigned short)((r >> 16) & 0xFFFEu));
        half2v aa = {ah, ah};
        half4v xh = *(const half4v*)(xl + (((size_t)(r & 0x1FFFFu)) << 6) + fl * 4);
        half2v x01 = {xh.x, xh.y}, x23 = {xh.z, xh.w};
        half2v v01 = aa * We01 + (x01 + xr01);
        half2v v23 = aa * We23 + (x23 + xr23);
        half2v s01 = __builtin_elementwise_max(v01, v01 * k02);
        half2v s23 = __builtin_elementwise_max(v23, v23 * k02);
#if __has_builtin(__builtin_amdgcn_fdot2)
        float c = __builtin_amdgcn_fdot2(s01, at01, 0.f, false);
        c = __builtin_amdgcn_fdot2(s23, at23, c, false);
#else
        float c = (float)s01.x * (float)at01.x + (float)s01.y * (float)at01.y
                + (float)s23.x * (float)at23.x + (float)s23.y * (float)at23.y;
#endif
#pragma unroll
        for (int mm = 1; mm <= 8; mm <<= 1) c += __shfl_xor(c, mm, 64);
        float q = valid ? __expf(c) : 0.f;
        l += q;
        O.x = fmaf(q, (float)xh.x, O.x);
        O.y = fmaf(q, (float)xh.y, O.y);
        O.z = fmaf(q, (float)xh.z, O.z);
        O.w = fmaf(q, (float)xh.w, O.w);
    }
#pragma unroll
    for (int mm = 16; mm <= 32; mm <<= 1) {
        l   += __shfl_xor(l, mm, 64);
        O.x += __shfl_xor(O.x, mm, 64);
        O.y += __shfl_xor(O.y, mm, 64);
        O.z += __shfl_xor(O.z, mm, 64);
        O.w += __shfl_xor(O.w, mm, 64);
    }
    if (eq == 0) {
        float inv = 1.0f / (l + 1e-16f);
        float4 b4 = *(const float4*)(bias + fl * 4);
        float4 res;
        res.x = fmaf(O.x, inv, b4.x);
        res.y = fmaf(O.y, inv, b4.y);
        res.z = fmaf(O.z, inv, b4.z);
        res.w = fmaf(O.w, inv, b4.w);
        res.x = res.x > 0.f ? res.x : expm1f(res.x);
        res.y = res.y > 0.f ? res.y : expm1f(res.y);
        res.z = res.z > 0.f ? res.z : expm1f(res.z);
        res.w = res.w > 0.f ? res.w : expm1f(res.w);
        *(float4*)(hout + ((size_t)d << 6) + fl * 4) = res;
    }
}

// ---------- pool (+ fused head in last-done block) ----------
__global__ void k_pool_head(const float* __restrict__ h, const int* __restrict__ batch,
                            float* __restrict__ pooled, float* __restrict__ gcnt,
                            int N, int npw, int* __restrict__ done,
                            const float* __restrict__ W1, const float* __restrict__ b1,
                            const float* __restrict__ gam, const float* __restrict__ bet,
                            const float* __restrict__ mu, const float* __restrict__ var,
                            const float* __restrict__ W3, const float* __restrict__ b3,
                            float* __restrict__ out, int G) {
    int tid = threadIdx.x;
    int lane = tid & 63;
    int wave = (int)(((size_t)blockIdx.x * blockDim.x + tid) >> 6);
    int begin = wave * npw;
    if (begin < N) {
        int end = begin + npw; if (end > N) end = N;
        int g = batch[begin];
        float acc = 0.f, cnt = 0.f;
        for (int n = begin; n < end; ++n) {
            int gn = batch[n];
            if (gn != g) {
                atomicAdd(&pooled[((size_t)g << 6) + lane], acc);
                if (lane == 0) atomicAdd(&gcnt[g], cnt);
                g = gn; acc = 0.f; cnt = 0.f;
            }
            acc += h[((size_t)n << 6) + lane];
            cnt += 1.f;
        }
        atomicAdd(&pooled[((size_t)g << 6) + lane], acc);
        if (lane == 0) atomicAdd(&gcnt[g], cnt);
    }
    __threadfence();
    __syncthreads();
    __shared__ int lastFlag;
    if (tid == 0) lastFlag = (atomicAdd(done, 1) == (int)gridDim.x - 1);
    __syncthreads();
    if (lastFlag && tid < G) {
        __threadfence();
        int g = tid;
        float inv = 1.0f / fmaxf(gcnt[g], 1.0f);
        float pr[64];
        for (int k = 0; k < 64; ++k) pr[k] = pooled[((size_t)g << 6) + k] * inv;
        float o = b3[0];
        for (int j = 0; j < 32; ++j) {
            float z = b1[j];
            for (int k = 0; k < 64; ++k) z += pr[k] * W1[k * 32 + j];
            z = fmaxf(z, 0.f);
            z = (z - mu[j]) / sqrtf(var[j] + 1e-5f) * gam[j] + bet[j];
            o += z * W3[j];
        }
        out[g] = o;
    }
}

// ---------- launch ----------
extern "C" void kernel_launch(void* const* d_in, const int* in_sizes, int n_in,
                              void* d_out, int out_size, void* d_ws, size_t ws_size,
                              hipStream_t stream) {
    const float* x    = (const float*)d_in[0];
    const int*   ei   = (const int*)d_in[1];
    const float* ea   = (const float*)d_in[2];
    const int*   batch= (const int*)d_in[3];
    const float* Wl1  = (const float*)d_in[4];
    const float* bl1  = (const float*)d_in[5];
    const float* Wr1  = (const float*)d_in[6];
    const float* br1  = (const float*)d_in[7];
    const float* We1  = (const float*)d_in[8];
    const float* att1 = (const float*)d_in[9];
    const float* bi1  = (const float*)d_in[10];
    const float* Wl2  = (const float*)d_in[11];
    const float* bl2  = (const float*)d_in[12];
    const float* Wr2  = (const float*)d_in[13];
    const float* br2  = (const float*)d_in[14];
    const float* We2  = (const float*)d_in[15];
    const float* att2 = (const float*)d_in[16];
    const float* bi2  = (const float*)d_in[17];
    const float* Wf1  = (const float*)d_in[18];
    const float* bf1  = (const float*)d_in[19];
    const float* gam  = (const float*)d_in[20];
    const float* bet  = (const float*)d_in[21];
    const float* mu   = (const float*)d_in[22];
    const float* var  = (const float*)d_in[23];
    const float* Wf3  = (const float*)d_in[24];
    const float* bf3  = (const float*)d_in[25];

    const int N    = in_sizes[3];          // 50000
    const int E    = in_sizes[2];          // 1600000
    const int INd  = in_sizes[0] / N;      // 128
    const int ld1  = (INd == 128) ? 7 : 6;
    const int Etot = E + N;
    const int G    = out_size;             // 64
    const int NB   = (N + 255) / 256;      // buckets (<=256)

    // workspace carve-up (256B aligned)
    char* w = (char*)d_ws;
    auto carve = [&](size_t bytes) { char* p = w; w += (bytes + 255) & ~(size_t)255; return p; };
    __half*   xl       = (__half*)  carve((size_t)N * 64 * 2);
    __half*   xr       = (__half*)  carve((size_t)N * 64 * 2);
    float*    hbuf     = (float*)   carve((size_t)N * 64 * 4);
    unsigned* csr      = (unsigned*)carve((size_t)(Etot + 8) * 4);
    u64*      queue    = (u64*)     carve((size_t)E * 8);
    int*      row_start= (int*)     carve((size_t)(N + 1) * 4);
    int*      qcount   = (int*)     carve((size_t)256 * 4);
    int*      qbase    = (int*)     carve((size_t)257 * 4);
    int*      qtail    = (int*)     carve((size_t)256 * 4);
    int*      csrbase  = (int*)     carve((size_t)257 * 4);
    float*    pooled   = (float*)   carve((size_t)G * 64 * 4);
    float*    gcnt     = (float*)   carve((size_t)G * 4);
    int*      done     = (int*)     carve(256);

    const int TB = 256;
    const int nbXF = (N + 63) / 64;              // node-transform blocks (64 nodes)
    const int attnBlocks = (N + 3) / 4;          // wave per dst, 4 waves/block

    // ---- CSR build start ----
    hipMemsetAsync(qcount, 0, 256 * 4, stream);
    const int hepb = 8192;
    k_hist<<<(E + hepb - 1) / hepb, TB, 0, stream>>>(ei, qcount, E, hepb);
    k_bscan<<<1, 256, 0, stream>>>(qcount, qbase, qtail, csrbase, row_start, N, E, NB,
                                   pooled, gcnt, done, G);
    // ---- fused: layer-1 node transform || edge partition ----
    const int nbPart = (E + PEPB - 1) / PEPB;
    k_xf1_part<<<nbXF + nbPart, TB, 0, stream>>>(x, ld1, Wl1, bl1, Wr1, br1, xl, xr, N, nbXF,
                                                 ei, ea, qtail, queue, E);
    k_build<<<NB, 1024, 0, stream>>>(queue, qbase, csrbase, row_start, csr, N);

    // ---- layer 1 edge phase ----
    k_attn<<<attnBlocks, TB, 0, stream>>>(xl, xr, csr, row_start, We1, att1, bi1, hbuf, N);

    // ---- layer 2 ----
    k_node_xf<<<nbXF, TB, 0, stream>>>(hbuf, 6, Wl2, bl2, Wr2, br2, xl, xr, N);
    k_attn<<<attnBlocks, TB, 0, stream>>>(xl, xr, csr, row_start, We2, att2, bi2, hbuf, N);

    // ---- pool + head (fused) ----
    const int npw = 64;
    const int poolWaves = (N + npw - 1) / npw;
    k_pool_head<<<(poolWaves * 64 + TB - 1) / TB, TB, 0, stream>>>(
        hbuf, batch, pooled, gcnt, N, npw, done,
        Wf1, bf1, gam, bet, mu, var, Wf3, bf3, (float*)d_out, G);
}

// Round 16
// 358.090 us; speedup vs baseline: 1.0413x; 1.0316x over previous
//
#include <hip/hip_runtime.h>
#include <hip/hip_fp16.h>
#include <math.h>

typedef unsigned long long u64;
typedef __attribute__((ext_vector_type(2))) _Float16 half2v;
typedef __attribute__((ext_vector_type(4))) _Float16 half4v;

// ============================================================================
// CSR build v4: NO histogram pass. Partition writes into fixed-capacity
// per-bucket queues (64 dsts/bucket, CAP slack, reservation via qtail atomic);
// bscan derives csr bases from measured counts; build = 782 blocks (was 196).
// Edge record u32 in csr: [31:17]=fp16-attr-bits>>1, [16:0]=src.
// Queue record u64: [47:24]=attr fixed-24, [22:17]=dst&63, [16:0]=src.
// Edge phase: wave per dst, 16-lane x 4-edge packed fp16, UNROLL x4
// (16 edges in flight). Head fused into pool via last-block-done counter.
// ============================================================================

#define CAP     3008    // queue slots per bucket (mean 2048, sigma ~45)
#define MAXSPAN 3072    // csr slots per bucket (edges + 64 self-loops)
#define PEPB    4096    // edges per partition block

// ---------- node transform core: 64 nodes/block, 16 nodes/wave, fp16 rows ----------
__device__ __forceinline__ void xf_block(
        const float* __restrict__ h, int ld,
        const float* __restrict__ Wl, const float* __restrict__ bl,
        const float* __restrict__ Wr, const float* __restrict__ br,
        __half* __restrict__ xl, __half* __restrict__ xr,
        int N, int node0, _Float16* rows, int t) {
    int in_dim = 1 << ld;
    int q = in_dim >> 2;            // 4-element chunks per row
    for (int idx = t; idx < 64 * q; idx += 256) {
        int nn = idx >> (ld - 2);
        int kk = (idx & (q - 1)) << 2;
        int node = node0 + nn;
        float4 v = {0.f, 0.f, 0.f, 0.f};
        if (node < N) v = *(const float4*)(h + (((size_t)node) << ld) + kk);
        half4v hv = {(_Float16)v.x, (_Float16)v.y, (_Float16)v.z, (_Float16)v.w};
        *(half4v*)(rows + (nn << ld) + kk) = hv;
    }
    __syncthreads();
    int lane = t & 63, w = t >> 6;
    int nb = w * 16;
    float al[16], ar[16];
    float blv = bl[lane], brv = br[lane];
#pragma unroll
    for (int i = 0; i < 16; ++i) { al[i] = blv; ar[i] = brv; }
    for (int k = 0; k < in_dim; k += 4) {
        float wl0 = Wl[(k + 0) * 64 + lane], wl1 = Wl[(k + 1) * 64 + lane];
        float wl2 = Wl[(k + 2) * 64 + lane], wl3 = Wl[(k + 3) * 64 + lane];
        float wr0 = Wr[(k + 0) * 64 + lane], wr1 = Wr[(k + 1) * 64 + lane];
        float wr2 = Wr[(k + 2) * 64 + lane], wr3 = Wr[(k + 3) * 64 + lane];
#pragma unroll
        for (int i = 0; i < 16; ++i) {
            half4v r = *(const half4v*)(rows + ((nb + i) << ld) + k);  // broadcast
            al[i] = fmaf((float)r.x, wl0, al[i]); al[i] = fmaf((float)r.y, wl1, al[i]);
            al[i] = fmaf((float)r.z, wl2, al[i]); al[i] = fmaf((float)r.w, wl3, al[i]);
            ar[i] = fmaf((float)r.x, wr0, ar[i]); ar[i] = fmaf((float)r.y, wr1, ar[i]);
            ar[i] = fmaf((float)r.z, wr2, ar[i]); ar[i] = fmaf((float)r.w, wr3, ar[i]);
        }
    }
#pragma unroll
    for (int i = 0; i < 16; ++i) {
        int node = node0 + nb + i;
        if (node < N) {
            xl[((size_t)node << 6) + lane] = __float2half(al[i]);
            xr[((size_t)node << 6) + lane] = __float2half(ar[i]);
        }
    }
}

// shared-memory union: xf rows (16 KB) vs partition arrays (9.6 KB)
union XfPartSmem {
    _Float16 rows[64 * 128];
    struct { int lh[800]; int lbase[800]; int lcur[800]; } p;
};

// FUSED: blocks [0,nbXF) = layer-1 node transform; blocks [nbXF,..) = partition
__global__ void k_xf1_part(
        const float* __restrict__ h, int ld,
        const float* __restrict__ Wl, const float* __restrict__ bl,
        const float* __restrict__ Wr, const float* __restrict__ br,
        __half* __restrict__ xl, __half* __restrict__ xr, int N, int nbXF,
        const int* __restrict__ ei, const float* __restrict__ ea,
        int* __restrict__ qtail, u64* __restrict__ queue, int E, int NB) {
    __shared__ XfPartSmem sm;
    int t = threadIdx.x;
    if (blockIdx.x < nbXF) {
        xf_block(h, ld, Wl, bl, Wr, br, xl, xr, N, blockIdx.x * 64, sm.rows, t);
    } else {
        int pb = blockIdx.x - nbXF;
        for (int i = t; i < NB; i += 256) { sm.p.lh[i] = 0; sm.p.lcur[i] = 0; }
        __syncthreads();
        int base = pb * PEPB;
        int end = base + PEPB; if (end > E) end = E;
        int dreg[PEPB / 256];
#pragma unroll
        for (int k = 0; k < PEPB / 256; ++k) {
            int e = base + t + k * 256;
            if (e < end) {
                dreg[k] = ei[E + e];
                atomicAdd(&sm.p.lh[dreg[k] >> 6], 1);
            }
        }
        __syncthreads();
        for (int i = t; i < NB; i += 256)
            if (sm.p.lh[i]) sm.p.lbase[i] = atomicAdd(&qtail[i], sm.p.lh[i]);
        __syncthreads();
#pragma unroll
        for (int k = 0; k < PEPB / 256; ++k) {
            int e = base + t + k * 256;
            if (e < end) {
                int d = dreg[k];
                int src = ei[e];
                float a = ea[e];
                int b = d >> 6;
                int idx = atomicAdd(&sm.p.lcur[b], 1);
                unsigned aq = (unsigned)(a * 16777216.0f);    // fixed-24, attr in [0,1)
                queue[(size_t)b * CAP + sm.p.lbase[b] + idx] =
                    (((u64)aq) << 24) | (((u64)(d & 63)) << 17) | (unsigned)src;
            }
        }
    }
}

// single block AFTER partition: csr bases from measured counts; zero pool state
__global__ void __launch_bounds__(1024)
k_bscan(const int* __restrict__ qtail, int* __restrict__ csrbase,
        int* __restrict__ row_start, int N, int NB,
        float* __restrict__ pooled, float* __restrict__ gcnt,
        int* __restrict__ done, int G) {
    __shared__ int s2[1024];
    int t = threadIdx.x;
    for (int i = t; i < G * 64; i += 1024) pooled[i] = 0.f;
    if (t < G) gcnt[t] = 0.f;
    if (t == 0) *done = 0;
    int lo = t << 6;
    int ndst = (lo < N) ? ((N - lo < 64) ? (N - lo) : 64) : 0;
    int cnt = (t < NB) ? qtail[t] : 0;
    int span = cnt + ndst;
    s2[t] = span;
    __syncthreads();
    for (int off = 1; off < 1024; off <<= 1) {
        int a = (t >= off) ? s2[t - off] : 0;
        __syncthreads();
        s2[t] += a;
        __syncthreads();
    }
    if (t < NB) csrbase[t] = s2[t] - span;       // exclusive
    if (t == 1023) {
        csrbase[NB] = s2[1023];
        row_start[N] = s2[1023];
    }
}

__device__ __forceinline__ unsigned attr_q15(float a) {
    unsigned short hb = __builtin_bit_cast(unsigned short, (_Float16)a);
    return (unsigned)(hb >> 1);       // attr in [0,1) -> fp16 top bit 0
}

// one block per 64-dst bucket (782 blocks): count+scan+scatter in LDS, flush
__global__ void k_build(const u64* __restrict__ queue, const int* __restrict__ qtail,
                        const int* __restrict__ csrbase,
                        int* __restrict__ row_start, unsigned* __restrict__ csr, int N) {
    __shared__ u64 stat[64];
    __shared__ int fill[64], sc[64];
    __shared__ unsigned lcsr[MAXSPAN];
    int t = threadIdx.x, b = blockIdx.x;
    if (t < 64) stat[t] = 0;
    __syncthreads();
    int cnt = qtail[b];
    size_t q0 = (size_t)b * CAP;
    for (int i = t; i < cnt; i += 256) {
        u64 r = queue[q0 + i];
        int dl = (int)((r >> 17) & 63);
        atomicAdd(&stat[dl], (1ULL << 32) | (unsigned)(r >> 24));
    }
    __syncthreads();
    int dg = (b << 6) + t;
    u64 p = (t < 64) ? stat[t] : 0;
    int deg = (int)(p >> 32);
    int v = (t < 64 && dg < N) ? deg + 1 : 0;
    if (t < 64) sc[t] = v;
    __syncthreads();
    for (int off = 1; off < 64; off <<= 1) {
        int a = (t >= off && t < 64) ? sc[t - off] : 0;
        __syncthreads();
        if (t < 64) sc[t] += a;
        __syncthreads();
    }
    if (t < 64 && dg < N) {
        int basel = sc[t] - v;   // exclusive
        row_start[dg] = csrbase[b] + basel;
        fill[t] = basel;
        float mean = ((float)(unsigned)p * (1.0f / 16777216.0f)) / fmaxf((float)deg, 1.0f);
        if (basel + deg < MAXSPAN) lcsr[basel + deg] = (attr_q15(mean) << 17) | (unsigned)dg;
    }
    __syncthreads();
    for (int i = t; i < cnt; i += 256) {
        u64 r = queue[q0 + i];
        int dl = (int)((r >> 17) & 63);
        int pos = atomicAdd(&fill[dl], 1);
        float av = (float)(unsigned)(r >> 24) * (1.0f / 16777216.0f);
        if (pos < MAXSPAN) lcsr[pos] = (attr_q15(av) << 17) | (unsigned)(r & 0x1FFFFu);
    }
    __syncthreads();
    int c0 = csrbase[b], span = csrbase[b + 1] - c0;
    if (span > MAXSPAN) span = MAXSPAN;
    for (int j = t; j < span; j += 256) csr[c0 + j] = lcsr[j];
}

// ---------- node transform (standalone, layer 2: ld=6 -> 8 KB rows) ----------
__global__ void k_node_xf(const float* __restrict__ h, int ld,
                          const float* __restrict__ Wl, const float* __restrict__ bl,
                          const float* __restrict__ Wr, const float* __restrict__ br,
                          __half* __restrict__ xl, __half* __restrict__ xr, int N) {
    __shared__ _Float16 rows[64 * 64];
    xf_block(h, ld, Wl, bl, Wr, br, xl, xr, N, blockIdx.x * 64, rows, threadIdx.x);
}

// ---------- edge micro-step: one 4-edge group ----------
#define EDGE_GROUP(r, xh, cc)                                                  \
    {                                                                          \
        _Float16 ah = __builtin_bit_cast(_Float16, (unsigned short)((r >> 16) & 0xFFFEu)); \
        half2v aa = {ah, ah};                                                  \
        half2v x01 = {xh.x, xh.y}, x23 = {xh.z, xh.w};                         \
        half2v v01 = aa * We01 + (x01 + xr01);                                 \
        half2v v23 = aa * We23 + (x23 + xr23);                                 \
        half2v s01 = __builtin_elementwise_max(v01, v01 * k02);                \
        half2v s23 = __builtin_elementwise_max(v23, v23 * k02);                \
        cc = __builtin_amdgcn_fdot2(s01, at01, 0.f, false);                    \
        cc = __builtin_amdgcn_fdot2(s23, at23, cc, false);                     \
    }

// ---------- fused edge phase: wave/dst, 16x4 packed fp16, unroll x4 ----------
__global__ void k_attn(const __half* __restrict__ xl, const __half* __restrict__ xr,
                       const unsigned* __restrict__ csr, const int* __restrict__ row_start,
                       const float* __restrict__ We, const float* __restrict__ att,
                       const float* __restrict__ bias,
                       float* __restrict__ hout, int N) {
    int lane = threadIdx.x & 63;
    int d = (int)(((size_t)blockIdx.x * blockDim.x + threadIdx.x) >> 6);
    if (d >= N) return;
    int eq = lane >> 4;           // which of 4 concurrent edges
    int fl = lane & 15;           // which 4-dim chunk of the 64 dims
    float4 Wef  = *(const float4*)(We + fl * 4);
    float4 attf = *(const float4*)(att + fl * 4);
    half2v We01 = {(_Float16)Wef.x, (_Float16)Wef.y};
    half2v We23 = {(_Float16)Wef.z, (_Float16)Wef.w};
    half2v at01 = {(_Float16)attf.x, (_Float16)attf.y};
    half2v at23 = {(_Float16)attf.z, (_Float16)attf.w};
    half4v xrh = *(const half4v*)(xr + ((size_t)d << 6) + fl * 4);
    half2v xr01 = {xrh.x, xrh.y}, xr23 = {xrh.z, xrh.w};
    const half2v k02 = {(_Float16)0.2f, (_Float16)0.2f};
    int e0 = __builtin_amdgcn_readfirstlane(row_start[d]);
    int e1 = __builtin_amdgcn_readfirstlane(row_start[d + 1]);
    float l = 0.f;
    float4 O = {0.f, 0.f, 0.f, 0.f};
    int e = e0;
    for (; e + 16 <= e1; e += 16) {     // 16 edges in flight
        unsigned rA = csr[e + eq];
        unsigned rB = csr[e + 4 + eq];
        unsigned rC = csr[e + 8 + eq];
        unsigned rD = csr[e + 12 + eq];
        half4v xA = *(const half4v*)(xl + (((size_t)(rA & 0x1FFFFu)) << 6) + fl * 4);
        half4v xB = *(const half4v*)(xl + (((size_t)(rB & 0x1FFFFu)) << 6) + fl * 4);
        half4v xC = *(const half4v*)(xl + (((size_t)(rC & 0x1FFFFu)) << 6) + fl * 4);
        half4v xD = *(const half4v*)(xl + (((size_t)(rD & 0x1FFFFu)) << 6) + fl * 4);
        float cA, cB, cC, cD;
        EDGE_GROUP(rA, xA, cA);
        EDGE_GROUP(rB, xB, cB);
        EDGE_GROUP(rC, xC, cC);
        EDGE_GROUP(rD, xD, cD);
#pragma unroll
        for (int mm = 1; mm <= 8; mm <<= 1) {      // 4 interleaved butterflies
            cA += __shfl_xor(cA, mm, 64);
            cB += __shfl_xor(cB, mm, 64);
            cC += __shfl_xor(cC, mm, 64);
            cD += __shfl_xor(cD, mm, 64);
        }
        float qA = __expf(cA), qB = __expf(cB), qC = __expf(cC), qD = __expf(cD);
        l += (qA + qB) + (qC + qD);
        O.x = fmaf(qA, (float)xA.x, O.x); O.x = fmaf(qB, (float)xB.x, O.x);
        O.x = fmaf(qC, (float)xC.x, O.x); O.x = fmaf(qD, (float)xD.x, O.x);
        O.y = fmaf(qA, (float)xA.y, O.y); O.y = fmaf(qB, (float)xB.y, O.y);
        O.y = fmaf(qC, (float)xC.y, O.y); O.y = fmaf(qD, (float)xD.y, O.y);
        O.z = fmaf(qA, (float)xA.z, O.z); O.z = fmaf(qB, (float)xB.z, O.z);
        O.z = fmaf(qC, (float)xC.z, O.z); O.z = fmaf(qD, (float)xD.z, O.z);
        O.w = fmaf(qA, (float)xA.w, O.w); O.w = fmaf(qB, (float)xB.w, O.w);
        O.w = fmaf(qC, (float)xC.w, O.w); O.w = fmaf(qD, (float)xD.w, O.w);
    }
    for (; e < e1; e += 4) {            // tail with clamp
        int ee = e + eq;
        bool valid = ee < e1;
        unsigned r = csr[valid ? ee : (e1 - 1)];
        half4v xh = *(const half4v*)(xl + (((size_t)(r & 0x1FFFFu)) << 6) + fl * 4);
        float c;
        EDGE_GROUP(r, xh, c);
#pragma unroll
        for (int mm = 1; mm <= 8; mm <<= 1) c += __shfl_xor(c, mm, 64);
        float q = valid ? __expf(c) : 0.f;
        l += q;
        O.x = fmaf(q, (float)xh.x, O.x);
        O.y = fmaf(q, (float)xh.y, O.y);
        O.z = fmaf(q, (float)xh.z, O.z);
        O.w = fmaf(q, (float)xh.w, O.w);
    }
#pragma unroll
    for (int mm = 16; mm <= 32; mm <<= 1) {
        l   += __shfl_xor(l, mm, 64);
        O.x += __shfl_xor(O.x, mm, 64);
        O.y += __shfl_xor(O.y, mm, 64);
        O.z += __shfl_xor(O.z, mm, 64);
        O.w += __shfl_xor(O.w, mm, 64);
    }
    if (eq == 0) {
        float inv = 1.0f / (l + 1e-16f);
        float4 b4 = *(const float4*)(bias + fl * 4);
        float4 res;
        res.x = fmaf(O.x, inv, b4.x);
        res.y = fmaf(O.y, inv, b4.y);
        res.z = fmaf(O.z, inv, b4.z);
        res.w = fmaf(O.w, inv, b4.w);
        res.x = res.x > 0.f ? res.x : expm1f(res.x);
        res.y = res.y > 0.f ? res.y : expm1f(res.y);
        res.z = res.z > 0.f ? res.z : expm1f(res.z);
        res.w = res.w > 0.f ? res.w : expm1f(res.w);
        *(float4*)(hout + ((size_t)d << 6) + fl * 4) = res;
    }
}

// ---------- pool (+ fused head in last-done block) ----------
__global__ void k_pool_head(const float* __restrict__ h, const int* __restrict__ batch,
                            float* __restrict__ pooled, float* __restrict__ gcnt,
                            int N, int npw, int* __restrict__ done,
                            const float* __restrict__ W1, const float* __restrict__ b1,
                            const float* __restrict__ gam, const float* __restrict__ bet,
                            const float* __restrict__ mu, const float* __restrict__ var,
                            const float* __restrict__ W3, const float* __restrict__ b3,
                            float* __restrict__ out, int G) {
    int tid = threadIdx.x;
    int lane = tid & 63;
    int wave = (int)(((size_t)blockIdx.x * blockDim.x + tid) >> 6);
    int begin = wave * npw;
    if (begin < N) {
        int end = begin + npw; if (end > N) end = N;
        int g = batch[begin];
        float acc = 0.f, cnt = 0.f;
        for (int n = begin; n < end; ++n) {
            int gn = batch[n];
            if (gn != g) {
                atomicAdd(&pooled[((size_t)g << 6) + lane], acc);
                if (lane == 0) atomicAdd(&gcnt[g], cnt);
                g = gn; acc = 0.f; cnt = 0.f;
            }
            acc += h[((size_t)n << 6) + lane];
            cnt += 1.f;
        }
        atomicAdd(&pooled[((size_t)g << 6) + lane], acc);
        if (lane == 0) atomicAdd(&gcnt[g], cnt);
    }
    __threadfence();
    __syncthreads();
    __shared__ int lastFlag;
    if (tid == 0) lastFlag = (atomicAdd(done, 1) == (int)gridDim.x - 1);
    __syncthreads();
    if (lastFlag && tid < G) {
        __threadfence();
        int g = tid;
        float inv = 1.0f / fmaxf(gcnt[g], 1.0f);
        float pr[64];
        for (int k = 0; k < 64; ++k) pr[k] = pooled[((size_t)g << 6) + k] * inv;
        float o = b3[0];
        for (int j = 0; j < 32; ++j) {
            float z = b1[j];
            for (int k = 0; k < 64; ++k) z += pr[k] * W1[k * 32 + j];
            z = fmaxf(z, 0.f);
            z = (z - mu[j]) / sqrtf(var[j] + 1e-5f) * gam[j] + bet[j];
            o += z * W3[j];
        }
        out[g] = o;
    }
}

// ---------- launch ----------
extern "C" void kernel_launch(void* const* d_in, const int* in_sizes, int n_in,
                              void* d_out, int out_size, void* d_ws, size_t ws_size,
                              hipStream_t stream) {
    const float* x    = (const float*)d_in[0];
    const int*   ei   = (const int*)d_in[1];
    const float* ea   = (const float*)d_in[2];
    const int*   batch= (const int*)d_in[3];
    const float* Wl1  = (const float*)d_in[4];
    const float* bl1  = (const float*)d_in[5];
    const float* Wr1  = (const float*)d_in[6];
    const float* br1  = (const float*)d_in[7];
    const float* We1  = (const float*)d_in[8];
    const float* att1 = (const float*)d_in[9];
    const float* bi1  = (const float*)d_in[10];
    const float* Wl2  = (const float*)d_in[11];
    const float* bl2  = (const float*)d_in[12];
    const float* Wr2  = (const float*)d_in[13];
    const float* br2  = (const float*)d_in[14];
    const float* We2  = (const float*)d_in[15];
    const float* att2 = (const float*)d_in[16];
    const float* bi2  = (const float*)d_in[17];
    const float* Wf1  = (const float*)d_in[18];
    const float* bf1  = (const float*)d_in[19];
    const float* gam  = (const float*)d_in[20];
    const float* bet  = (const float*)d_in[21];
    const float* mu   = (const float*)d_in[22];
    const float* var  = (const float*)d_in[23];
    const float* Wf3  = (const float*)d_in[24];
    const float* bf3  = (const float*)d_in[25];

    const int N    = in_sizes[3];          // 50000
    const int E    = in_sizes[2];          // 1600000
    const int INd  = in_sizes[0] / N;      // 128
    const int ld1  = (INd == 128) ? 7 : 6;
    const int Etot = E + N;
    const int G    = out_size;             // 64
    const int NB   = (N + 63) / 64;        // 64-dst buckets (<=1024)

    // workspace carve-up (256B aligned)
    char* w = (char*)d_ws;
    auto carve = [&](size_t bytes) { char* p = w; w += (bytes + 255) & ~(size_t)255; return p; };
    __half*   xl       = (__half*)  carve((size_t)N * 64 * 2);
    __half*   xr       = (__half*)  carve((size_t)N * 64 * 2);
    float*    hbuf     = (float*)   carve((size_t)N * 64 * 4);
    unsigned* csr      = (unsigned*)carve((size_t)(Etot + 16) * 4);
    u64*      queue    = (u64*)     carve((size_t)NB * CAP * 8);
    int*      row_start= (int*)     carve((size_t)(N + 1) * 4);
    int*      qtail    = (int*)     carve((size_t)(NB + 1) * 4);
    int*      csrbase  = (int*)     carve((size_t)(NB + 1) * 4);
    float*    pooled   = (float*)   carve((size_t)G * 64 * 4);
    float*    gcnt     = (float*)   carve((size_t)G * 4);
    int*      done     = (int*)     carve(256);

    const int TB = 256;
    const int nbXF = (N + 63) / 64;              // node-transform blocks
    const int attnBlocks = (N + 3) / 4;          // wave per dst, 4 waves/block
    const int nbPart = (E + PEPB - 1) / PEPB;

    // ---- CSR build: partition (fused w/ layer-1 xf) -> bscan -> build ----
    hipMemsetAsync(qtail, 0, (size_t)(NB + 1) * 4, stream);
    k_xf1_part<<<nbXF + nbPart, TB, 0, stream>>>(x, ld1, Wl1, bl1, Wr1, br1, xl, xr, N, nbXF,
                                                 ei, ea, qtail, queue, E, NB);
    k_bscan<<<1, 1024, 0, stream>>>(qtail, csrbase, row_start, N, NB,
                                    pooled, gcnt, done, G);
    k_build<<<NB, TB, 0, stream>>>(queue, qtail, csrbase, row_start, csr, N);

    // ---- layer 1 edge phase ----
    k_attn<<<attnBlocks, TB, 0, stream>>>(xl, xr, csr, row_start, We1, att1, bi1, hbuf, N);

    // ---- layer 2 ----
    k_node_xf<<<nbXF, TB, 0, stream>>>(hbuf, 6, Wl2, bl2, Wr2, br2, xl, xr, N);
    k_attn<<<attnBlocks, TB, 0, stream>>>(xl, xr, csr, row_start, We2, att2, bi2, hbuf, N);

    // ---- pool + head (fused) ----
    const int npw = 64;
    const int poolWaves = (N + npw - 1) / npw;
    k_pool_head<<<(poolWaves * 64 + TB - 1) / TB, TB, 0, stream>>>(
        hbuf, batch, pooled, gcnt, N, npw, done,
        Wf1, bf1, gam, bet, mu, var, Wf3, bf3, (float*)d_out, G);
}